// Round 14
// baseline (554.477 us; speedup 1.0000x reference)
//
#include <hip/hip_runtime.h>

#define RES  512
#define LTOK (RES*RES)
#define DIMC 64
#define HIDC 256
#define NWIN 4096

typedef unsigned short bfu;
typedef __attribute__((ext_vector_type(8))) short s16x8;
typedef __attribute__((ext_vector_type(4))) float f32x4;

#define MFMA(a,b,c) __builtin_amdgcn_mfma_f32_16x16x32_bf16((a),(b),(c),0,0,0)

__device__ inline bfu f2bf(float f) {
    unsigned b = __float_as_uint(f);
    return (bfu)((b + 0x7FFFu + ((b >> 16) & 1u)) >> 16);
}
__device__ inline float bf2f(bfu u) { return __uint_as_float((unsigned)u << 16); }
__device__ inline ushort4 pack4(float a, float b, float c, float d) {
    ushort4 r; r.x = f2bf(a); r.y = f2bf(b); r.z = f2bf(c); r.w = f2bf(d); return r;
}

// Chunked fragment layout for 64x64 bf16 matrix M[row][k]:
//   element (row,k) at ushort index ((k>>3)*64 + row)*8 + (k&7)
__device__ inline s16x8 fldl(const ushort* buf, int chunkbase, int rowbase, int g, int li) {
    return *(const s16x8*)&buf[((chunkbase + g) * 64 + rowbase + li) * 8];
}
__device__ inline s16x8 fldg(const ushort* w, int rowbase, int ks, int g, int li) {
    return *(const s16x8*)&w[(rowbase + li) * 64 + 32 * ks + 8 * g];
}

// LayerNorm, 512-thread version: 8 lanes per token, 8 channels each.
__device__ inline void ln_win512(const float* __restrict__ src,
                                 const float* __restrict__ lw, const float* __restrict__ lb,
                                 ushort* dsth, ushort* dstl, int wi, int wj, int tid)
{
    const int n = tid >> 3, p = tid & 7;
    const int gtok = (wi * 8 + (n >> 3)) * RES + wj * 8 + (n & 7);
    const float* rp = src + (size_t)gtok * DIMC + p * 8;
    float v[8];
    *(float4*)&v[0] = *(const float4*)&rp[0];
    *(float4*)&v[4] = *(const float4*)&rp[4];
    float s = 0.f, s2 = 0.f;
    #pragma unroll
    for (int j = 0; j < 8; ++j) { s += v[j]; s2 += v[j] * v[j]; }
    s  += __shfl_xor(s, 1);  s  += __shfl_xor(s, 2);  s  += __shfl_xor(s, 4);
    s2 += __shfl_xor(s2, 1); s2 += __shfl_xor(s2, 2); s2 += __shfl_xor(s2, 4);
    const float mean = s * 0.015625f;
    const float var  = s2 * 0.015625f - mean * mean;
    const float rs = rsqrtf(var + 1e-5f);
    float wv[8], bv[8];
    *(float4*)&wv[0] = *(const float4*)&lw[p*8+0];  *(float4*)&bv[0] = *(const float4*)&lb[p*8+0];
    *(float4*)&wv[4] = *(const float4*)&lw[p*8+4];  *(float4*)&bv[4] = *(const float4*)&lb[p*8+4];
    unsigned pkh[4], pkl[4];
    #pragma unroll
    for (int j = 0; j < 4; ++j) {
        float a = (v[2*j]   - mean) * rs * wv[2*j]   + bv[2*j];
        float b = (v[2*j+1] - mean) * rs * wv[2*j+1] + bv[2*j+1];
        bfu ha = f2bf(a), hb = f2bf(b);
        bfu la = f2bf(a - bf2f(ha)), lb2 = f2bf(b - bf2f(hb));
        pkh[j] = (unsigned)ha | ((unsigned)hb << 16);
        pkl[j] = (unsigned)la | ((unsigned)lb2 << 16);
    }
    *(int4*)&dsth[(p * 64 + n) * 8] = *(const int4*)&pkh[0];
    *(int4*)&dstl[(p * 64 + n) * 8] = *(const int4*)&pkl[0];
}

// Split-precision transposed projection, HALF version: ct in {2cth, 2cth+1}.
__device__ inline void gemmT3h(const ushort* __restrict__ wTh, const ushort* __restrict__ wTl,
                               const ushort* xh, const ushort* xl,
                               const float* __restrict__ biasv,
                               ushort* dst, int w, int cth, int g, int li)
{
    const s16x8 ah0 = fldg(wTh, 16*w, 0, g, li);
    const s16x8 ah1 = fldg(wTh, 16*w, 1, g, li);
    const s16x8 al0 = fldg(wTl, 16*w, 0, g, li);
    const s16x8 al1 = fldg(wTl, 16*w, 1, g, li);
    const float4 bias = *(const float4*)&biasv[16*w + 4*g];
    #pragma unroll
    for (int c2 = 0; c2 < 2; ++c2) {
        const int ct = 2*cth + c2;
        const s16x8 bh0 = fldl(xh, 0, 16*ct, g, li);
        const s16x8 bh1 = fldl(xh, 4, 16*ct, g, li);
        const s16x8 bl0 = fldl(xl, 0, 16*ct, g, li);
        const s16x8 bl1 = fldl(xl, 4, 16*ct, g, li);
        f32x4 acc = {0.f, 0.f, 0.f, 0.f};
        acc = MFMA(al0, bh0, acc);
        acc = MFMA(al1, bh1, acc);
        acc = MFMA(ah0, bl0, acc);
        acc = MFMA(ah1, bl1, acc);
        acc = MFMA(ah0, bh0, acc);
        acc = MFMA(ah1, bh1, acc);
        *(ushort4*)&dst[((2*w + (g>>1)) * 64 + 16*ct + li) * 8 + (g&1)*4] =
            pack4(acc[0]+bias.x, acc[1]+bias.y, acc[2]+bias.z, acc[3]+bias.w);
    }
}

// HALF version, f32 store (stride 68): token = 16ct+li, channel = 16w+4g+r.
__device__ inline void gemmT3fh(const ushort* __restrict__ wTh, const ushort* __restrict__ wTl,
                                const ushort* xh, const ushort* xl,
                                const float* __restrict__ biasv,
                                float* dst, int w, int cth, int g, int li)
{
    const s16x8 ah0 = fldg(wTh, 16*w, 0, g, li);
    const s16x8 ah1 = fldg(wTh, 16*w, 1, g, li);
    const s16x8 al0 = fldg(wTl, 16*w, 0, g, li);
    const s16x8 al1 = fldg(wTl, 16*w, 1, g, li);
    const float4 bias = *(const float4*)&biasv[16*w + 4*g];
    #pragma unroll
    for (int c2 = 0; c2 < 2; ++c2) {
        const int ct = 2*cth + c2;
        const s16x8 bh0 = fldl(xh, 0, 16*ct, g, li);
        const s16x8 bh1 = fldl(xh, 4, 16*ct, g, li);
        const s16x8 bl0 = fldl(xl, 0, 16*ct, g, li);
        const s16x8 bl1 = fldl(xl, 4, 16*ct, g, li);
        f32x4 acc = {0.f, 0.f, 0.f, 0.f};
        acc = MFMA(al0, bh0, acc);
        acc = MFMA(al1, bh1, acc);
        acc = MFMA(ah0, bl0, acc);
        acc = MFMA(ah1, bl1, acc);
        acc = MFMA(ah0, bh0, acc);
        acc = MFMA(ah1, bh1, acc);
        float4 st = { acc[0]+bias.x, acc[1]+bias.y, acc[2]+bias.z, acc[3]+bias.w };
        *(float4*)&dst[(16*ct + li)*68 + 16*w + 4*g] = st;
    }
}

// ---------------------------------------------------------------------------
// Prep: attn tables (12 matrices, bsc, bias2) + fc1/fc2 transposed hi/lo.
// ---------------------------------------------------------------------------
__global__ __launch_bounds__(256) void k_prep(
    const float* __restrict__ wqx, const float* __restrict__ wkvx,
    const float* __restrict__ wqf, const float* __restrict__ wkvf,
    const float* __restrict__ projw, const float* __restrict__ bqx,
    const float* __restrict__ bqf, const float* __restrict__ rpb,
    const float* __restrict__ fc1w, const float* __restrict__ fc2w,
    ushort* __restrict__ wb, float* __restrict__ bsc, float* __restrict__ bias2)
{
    const float scale = 0.17677669529663687f;  // 32^-0.5
    int t = blockIdx.x * 256 + threadIdx.x;
    if (t < 49152) {
        int m = t >> 12, idx = t & 4095;
        int c = idx >> 6, k = idx & 63;
        int mm = m % 6;
        float val;
        switch (mm) {
            case 0:  val = wqx [k*64  + c] * scale; break;
            case 1:  val = wkvx[k*128 + c];         break;
            case 2:  val = wkvx[k*128 + 64 + c];    break;
            case 3:  val = wqf [k*64  + c] * scale; break;
            case 4:  val = wkvf[k*128 + c];         break;
            default: val = projw[k*64 + c];         break;
        }
        bfu h = f2bf(val);
        wb[m*4096 + c*64 + k] = (m < 6) ? h : f2bf(val - bf2f(h));
    } else if (t < 65536) {            // fc1^T hi+lo: [256 out][64 k]
        int i = t - 49152;
        int c = i >> 6, k = i & 63;
        float val = fc1w[k*HIDC + c];
        bfu h = f2bf(val);
        wb[49152 + i] = h;
        wb[65536 + i] = f2bf(val - bf2f(h));
    } else if (t < 81920) {            // fc2^T hi+lo: [64 out][256 k]
        int i = t - 65536;
        int c = i >> 8, k = i & 255;
        float val = fc2w[k*DIMC + c];
        bfu h = f2bf(val);
        wb[81920 + i] = h;
        wb[98304 + i] = f2bf(val - bf2f(h));
    } else if (t < 82048) {
        int i = t - 81920;
        bsc[i] = (i < 64) ? bqx[i] * scale : bqf[i-64] * scale;
    } else if (t < 90240) {
        int i = t - 82048;
        int h = i >> 12, rest = i & 4095;
        int n = rest >> 6, m2 = rest & 63;
        int idx = ((n>>3) - (m2>>3) + 7) * 15 + ((n&7) - (m2&7) + 7);
        bias2[h*4096 + rest] = rpb[idx*2 + h];
    }
}

// ---------------------------------------------------------------------------
// Kernel A: 512 threads / window. MFMA projections (ct-split over 8 waves)
// + fused register scores/softmax (R13 bit-exact) + f32 PV + LDS-staged proj
// + FUSED fc1: LN(xmid regs) -> split-MFMA fc1 -> y1 (replaces k_fc1).
// LDS map (bytes):
//   0      A      (8192)   8192  Alo  (8192)   16384 QF (8192)
//   24576  KF     (8192)  32768  Q    (8192)
//   40960  K f32  (17408) 58368  V f32 (17408)
//   P f32 [2][64][65] @ 0 (after Ph4 barrier; den in row[64]); O @ 33280
//   W f32 [64][68] @ 0 (after Ph5 barrier; P dead)
//   xn hi/lo chunked @ 0/8192 (after Ph6 barrier; W dead)
// ---------------------------------------------------------------------------
__global__ __launch_bounds__(512, 4) void k_attn(
    const float* __restrict__ x, const float* __restrict__ f,
    const float* __restrict__ n1w, const float* __restrict__ n1b,
    const float* __restrict__ n1fw, const float* __restrict__ n1fb,
    const float* __restrict__ bkvx, const float* __restrict__ bkvf,
    const float* __restrict__ projw32, const float* __restrict__ projb,
    const float* __restrict__ n2w, const float* __restrict__ n2b,
    const ushort* __restrict__ fc1h, const ushort* __restrict__ fc1l,
    const float* __restrict__ fc1b,
    const ushort* __restrict__ wbufs, const float* __restrict__ bsc,
    const float* __restrict__ bias2,
    float* __restrict__ xmid, bfu* __restrict__ y1)
{
    __shared__ __align__(16) unsigned char LDSRAW[75776];
    ushort* bufA   = (ushort*)(LDSRAW);
    ushort* bufAlo = (ushort*)(LDSRAW + 8192);
    ushort* bufQF  = (ushort*)(LDSRAW + 16384);
    ushort* bufKF  = (ushort*)(LDSRAW + 24576);
    ushort* bufQ   = (ushort*)(LDSRAW + 32768);
    float*  Kf32   = (float*)(LDSRAW + 40960);
    float*  Vf32   = (float*)(LDSRAW + 58368);
    float*  Pf     = (float*)(LDSRAW);            // [2][64][65]
    float*  Of     = (float*)(LDSRAW + 33280);    // [64][68]
    float*  Wlds   = (float*)(LDSRAW);            // [64][68] after Ph5

    const int tid = (int)threadIdx.x;
    const int wv = tid >> 6, lane = tid & 63, g = lane >> 4, li = lane & 15;
    const int wid = blockIdx.x, wi = wid >> 6, wj = wid & 63;
    const int w8 = wv & 3, cth = wv >> 2;         // gemm split

    const ushort* wqxTh  = wbufs;
    const ushort* wkxTh  = wbufs + 4096;
    const ushort* wvxTh  = wbufs + 8192;
    const ushort* wqfTh  = wbufs + 12288;
    const ushort* wkfTh  = wbufs + 16384;
    const ushort* wqxTl  = wbufs + 24576;
    const ushort* wkxTl  = wbufs + 28672;
    const ushort* wvxTl  = wbufs + 32768;
    const ushort* wqfTl  = wbufs + 36864;
    const ushort* wkfTl  = wbufs + 40960;
    const float* bqxs = bsc, * bqfs = bsc + 64;

    // Ph0: LN(f) -> A(hi), Alo(lo)
    ln_win512(f, n1fw, n1fb, bufA, bufAlo, wi, wj, tid);
    __syncthreads();

    // Ph1: qf -> QF, kf -> KF (each wave does half of each gemm)
    gemmT3h(wqfTh, wqfTl, bufA, bufAlo, bqfs, bufQF, w8, cth, g, li);
    gemmT3h(wkfTh, wkfTl, bufA, bufAlo, bkvf, bufKF, w8, cth, g, li);
    __syncthreads();

    // Ph2: LN(x) -> A/Alo (fn dead)
    ln_win512(x, n1w, n1b, bufA, bufAlo, wi, wj, tid);
    __syncthreads();

    // Ph3: q -> Q (bf16), k -> Kf32, v -> Vf32
    gemmT3h (wqxTh, wqxTl, bufA, bufAlo, bqxs,      bufQ, w8, cth, g, li);
    gemmT3fh(wkxTh, wkxTl, bufA, bufAlo, bkvx,      Kf32, w8, cth, g, li);
    gemmT3fh(wvxTh, wvxTl, bufA, bufAlo, bkvx + 64, Vf32, w8, cth, g, li);
    __syncthreads();

    // Ph4: fused S_f + S_x + joint logits + softmax, all in registers.
    // thread = (head h2, query q2, key-quarter kh); keys m = 4*mi + kh
    const int h2 = tid >> 8, q2 = (tid >> 2) & 63, kh = tid & 3;
    float p[16];
    float den;
    {
        float qfreg[32], qreg[32];
        #pragma unroll
        for (int cc = 0; cc < 4; ++cc) {
            const s16x8 qfv = *(const s16x8*)&bufQF[((4*h2+cc)*64 + q2)*8];
            const s16x8 qv  = *(const s16x8*)&bufQ [((4*h2+cc)*64 + q2)*8];
            #pragma unroll
            for (int j = 0; j < 8; ++j) {
                qfreg[8*cc+j] = bf2f((bfu)(unsigned short)qfv[j]);
                qreg [8*cc+j] = bf2f((bfu)(unsigned short)qv[j]);
            }
        }
        const float* brow = &bias2[h2*4096 + q2*64];
        float mx = -1e30f;
        #pragma unroll
        for (int mi = 0; mi < 16; ++mi) {
            const int m = 4*mi + kh;
            float sf = 0.f, sx = 0.f;
            #pragma unroll
            for (int cc = 0; cc < 4; ++cc) {
                const s16x8 kfv = *(const s16x8*)&bufKF[((4*h2+cc)*64 + m)*8];
                #pragma unroll
                for (int j = 0; j < 8; ++j) sf += qfreg[8*cc+j] * bf2f((bfu)(unsigned short)kfv[j]);
            }
            #pragma unroll
            for (int c4 = 0; c4 < 8; ++c4) {
                const float4 kv = *(const float4*)&Kf32[m*68 + 32*h2 + 4*c4];
                sx += qreg[4*c4+0]*kv.x + qreg[4*c4+1]*kv.y
                    + qreg[4*c4+2]*kv.z + qreg[4*c4+3]*kv.w;
            }
            const float b = brow[m];
            const float lv = (sx + b) * (sf + b);
            p[mi] = lv;
            mx = fmaxf(mx, lv);
        }
        mx = fmaxf(mx, __shfl_xor(mx, 1));
        mx = fmaxf(mx, __shfl_xor(mx, 2));
        den = 0.f;
        #pragma unroll
        for (int mi = 0; mi < 16; ++mi) {
            const float e = __expf(p[mi] - mx);
            p[mi] = e;
            den += e;
        }
        den += __shfl_xor(den, 1);
        den += __shfl_xor(den, 2);
    }
    __syncthreads();   // q/qf/kf/K reads complete; P may overwrite

    // Ph4b: P (f32, stride 65) -> Pf; den -> row slot 64
    {
        float* srow = &Pf[h2*4160 + q2*65];
        #pragma unroll
        for (int mi = 0; mi < 16; ++mi) srow[4*mi + kh] = p[mi];
        if (kh == 0) srow[64] = den;
    }
    __syncthreads();

    // Ph5: PV (f32). wave -> (head, channel-octet); lane = query
    {
        const int comp = wv;                 // 0..7
        const int head = comp >> 2, quarter = comp & 3;
        const int cbase = head*32 + quarter*8;
        const int n2 = lane;
        float acc[8];
        #pragma unroll
        for (int j = 0; j < 8; ++j) acc[j] = 0.f;
        const float* prow = &Pf[head*4160 + n2*65];
        for (int m = 0; m < 64; ++m) {
            const float pv = prow[m];
            #pragma unroll
            for (int c4 = 0; c4 < 2; ++c4) {
                const float4 vv = *(const float4*)&Vf32[m*68 + cbase + 4*c4];
                acc[4*c4+0] += pv * vv.x;
                acc[4*c4+1] += pv * vv.y;
                acc[4*c4+2] += pv * vv.z;
                acc[4*c4+3] += pv * vv.w;
            }
        }
        const float inv = 1.f / prow[64];
        #pragma unroll
        for (int j4 = 0; j4 < 2; ++j4) {
            float4 st = { acc[4*j4]*inv, acc[4*j4+1]*inv, acc[4*j4+2]*inv, acc[4*j4+3]*inv };
            *(float4*)&Of[n2*68 + cbase + 4*j4] = st;
        }
    }
    __syncthreads();   // P dead; W may overwrite

    // Ph5c: stage projw -> Wlds [64][68] (L2-hot 16KB, coalesced)
    {
        const int row = tid >> 3, c = (tid & 7) * 8;
        const float4 w0 = *(const float4*)&projw32[row*64 + c];
        const float4 w1 = *(const float4*)&projw32[row*64 + c + 4];
        *(float4*)&Wlds[row*68 + c]     = w0;
        *(float4*)&Wlds[row*68 + c + 4] = w1;
    }
    __syncthreads();

    // Ph6: proj from LDS + bias + residual -> xmid (regs kept for fused fc1).
    // thread = (token n, 8-channel group c0q)
    const int n6 = tid >> 3, c0q = (tid & 7) * 8;
    float xv[8];
    {
        *(float4*)&xv[0] = *(const float4*)&projb[c0q];
        *(float4*)&xv[4] = *(const float4*)&projb[c0q + 4];
        for (int kk = 0; kk < 64; ++kk) {
            const float a = Of[n6*68 + kk];
            const float* wr = Wlds + kk*68 + c0q;
            #pragma unroll
            for (int j = 0; j < 8; ++j) xv[j] += a * wr[j];
        }
        const int gtok = (wi*8 + (n6 >> 3)) * RES + wj*8 + (n6 & 7);
        const float4 r0 = *(const float4*)&x[(size_t)gtok*DIMC + c0q];
        const float4 r1 = *(const float4*)&x[(size_t)gtok*DIMC + c0q + 4];
        xv[0] += r0.x; xv[1] += r0.y; xv[2] += r0.z; xv[3] += r0.w;
        xv[4] += r1.x; xv[5] += r1.y; xv[6] += r1.z; xv[7] += r1.w;
        float4 o0 = { xv[0], xv[1], xv[2], xv[3] };
        float4 o1 = { xv[4], xv[5], xv[6], xv[7] };
        *(float4*)&xmid[(size_t)gtok*DIMC + c0q]     = o0;
        *(float4*)&xmid[(size_t)gtok*DIMC + c0q + 4] = o1;
    }
    __syncthreads();   // all Of/Wlds reads complete; xn may overwrite @0/@8192

    // Ph7a (fused fc1 LN): 8 lanes per token hold its 64 channels in xv.
    // Reduce across lanes (xor 1,2,4), normalize, pack hi/lo chunked -> A/Alo.
    {
        float s = 0.f, s2 = 0.f;
        #pragma unroll
        for (int j = 0; j < 8; ++j) { s += xv[j]; s2 += xv[j]*xv[j]; }
        s  += __shfl_xor(s, 1);  s  += __shfl_xor(s, 2);  s  += __shfl_xor(s, 4);
        s2 += __shfl_xor(s2, 1); s2 += __shfl_xor(s2, 2); s2 += __shfl_xor(s2, 4);
        const float mean = s * 0.015625f;
        const float var  = s2 * 0.015625f - mean * mean;
        const float rs = rsqrtf(var + 1e-5f);
        float wv2[8], bv2[8];
        *(float4*)&wv2[0] = *(const float4*)&n2w[c0q];     *(float4*)&bv2[0] = *(const float4*)&n2b[c0q];
        *(float4*)&wv2[4] = *(const float4*)&n2w[c0q + 4]; *(float4*)&bv2[4] = *(const float4*)&n2b[c0q + 4];
        unsigned pkh[4], pkl[4];
        #pragma unroll
        for (int j = 0; j < 4; ++j) {
            float a = (xv[2*j]   - mean) * rs * wv2[2*j]   + bv2[2*j];
            float b = (xv[2*j+1] - mean) * rs * wv2[2*j+1] + bv2[2*j+1];
            bfu ha = f2bf(a), hb = f2bf(b);
            bfu la = f2bf(a - bf2f(ha)), lb2 = f2bf(b - bf2f(hb));
            pkh[j] = (unsigned)ha | ((unsigned)hb << 16);
            pkl[j] = (unsigned)la | ((unsigned)lb2 << 16);
        }
        const int pc = tid & 7;
        *(int4*)&bufA  [(pc * 64 + n6) * 8] = *(const int4*)&pkh[0];
        *(int4*)&bufAlo[(pc * 64 + n6) * 8] = *(const int4*)&pkl[0];
    }
    __syncthreads();

    // Ph7b (fused fc1 gemm): wave handles out-tiles w = wv and wv+8 (256 ch).
    #pragma unroll
    for (int tt = 0; tt < 2; ++tt) {
        const int w = wv + 8*tt;
        const s16x8 ah0 = fldg(fc1h, 16*w, 0, g, li);
        const s16x8 ah1 = fldg(fc1h, 16*w, 1, g, li);
        const s16x8 al0 = fldg(fc1l, 16*w, 0, g, li);
        const s16x8 al1 = fldg(fc1l, 16*w, 1, g, li);
        const float4 bb = *(const float4*)&fc1b[16*w + 4*g];
        #pragma unroll
        for (int ct = 0; ct < 4; ++ct) {
            const s16x8 bh0 = fldl(bufA,   0, 16*ct, g, li);
            const s16x8 bh1 = fldl(bufA,   4, 16*ct, g, li);
            const s16x8 bl0 = fldl(bufAlo, 0, 16*ct, g, li);
            const s16x8 bl1 = fldl(bufAlo, 4, 16*ct, g, li);
            f32x4 acc = {0.f, 0.f, 0.f, 0.f};
            acc = MFMA(al0, bh0, acc);
            acc = MFMA(al1, bh1, acc);
            acc = MFMA(ah0, bl0, acc);
            acc = MFMA(ah1, bl1, acc);
            acc = MFMA(ah0, bh0, acc);
            acc = MFMA(ah1, bh1, acc);
            const int nt = 16*ct + li;
            const int gtok = (wi*8 + (nt >> 3)) * RES + wj*8 + (nt & 7);
            *(ushort4*)&y1[(size_t)gtok*HIDC + 16*w + 4*g] =
                pack4(acc[0]+bb.x, acc[1]+bb.y, acc[2]+bb.z, acc[3]+bb.w);
        }
    }
}

// ---------------------------------------------------------------------------
// Kernel C: depthwise 3x3 conv + relu (VALU) -> fc2 (split-MFMA, K=256)
// + bias + residual, in-place on d_out. Block = 32 tokens.
// ---------------------------------------------------------------------------
__global__ __launch_bounds__(256) void k_conv_fc2(
    const bfu* __restrict__ y1,
    const float* __restrict__ cw, const float* __restrict__ cb,
    const ushort* __restrict__ fc2h, const ushort* __restrict__ fc2l,
    const float* __restrict__ fc2b,
    float* __restrict__ xout)
{
    __shared__ float scw[2304];
    __shared__ __align__(16) ushort chH[8192], chL[8192];  // [32 tok][256 ch] chunked
    const int tid = (int)threadIdx.x, wv = tid >> 6, lane = tid & 63;
    const int g = lane >> 4, li = lane & 15;

    for (int i = tid; i < 2304; i += 256) scw[i] = cw[i];
    __syncthreads();

    const int base = blockIdx.x * 32;
    const int ch0 = lane * 4;

    float kw[4][9];
    #pragma unroll
    for (int j = 0; j < 4; ++j)
        #pragma unroll
        for (int kidx = 0; kidx < 9; ++kidx) kw[j][kidx] = scw[(ch0+j)*9 + kidx];
    const float cb0 = cb[ch0], cb1 = cb[ch0+1], cb2 = cb[ch0+2], cb3 = cb[ch0+3];

    for (int t = 0; t < 8; ++t) {
        const int tr = wv * 8 + t;
        const int tok = base + tr;
        const int hh = tok >> 9, ww = tok & 511;
        float a0 = cb0, a1 = cb1, a2 = cb2, a3 = cb3;
        #pragma unroll
        for (int dh = -1; dh <= 1; ++dh) {
            const int h2 = hh + dh;
            if (h2 < 0 || h2 >= RES) continue;
            #pragma unroll
            for (int dw = -1; dw <= 1; ++dw) {
                const int w2 = ww + dw;
                if (w2 < 0 || w2 >= RES) continue;
                const ushort4 u = *(const ushort4*)&y1[(size_t)(h2*RES + w2)*HIDC + ch0];
                const int kidx = (dh+1)*3 + (dw+1);
                a0 += bf2f(u.x) * kw[0][kidx];
                a1 += bf2f(u.y) * kw[1][kidx];
                a2 += bf2f(u.z) * kw[2][kidx];
                a3 += bf2f(u.w) * kw[3][kidx];
            }
        }
        a0 = fmaxf(a0, 0.f); a1 = fmaxf(a1, 0.f);
        a2 = fmaxf(a2, 0.f); a3 = fmaxf(a3, 0.f);
        ushort4 hi, lo;
        hi.x = f2bf(a0); lo.x = f2bf(a0 - bf2f(hi.x));
        hi.y = f2bf(a1); lo.y = f2bf(a1 - bf2f(hi.y));
        hi.z = f2bf(a2); lo.z = f2bf(a2 - bf2f(hi.z));
        hi.w = f2bf(a3); lo.w = f2bf(a3 - bf2f(hi.w));
        const int cidx = ((ch0 >> 3) * 32 + tr) * 8 + (ch0 & 7);
        *(ushort4*)&chH[cidx] = hi;
        *(ushort4*)&chL[cidx] = lo;
    }
    __syncthreads();

    // fc2: wave wv -> out-channel tile 16*wv; K=256 (8 k-steps x 3 split terms)
    {
        const int chb = 16 * wv;
        f32x4 accA = {0.f, 0.f, 0.f, 0.f};
        f32x4 accB = {0.f, 0.f, 0.f, 0.f};
        #pragma unroll
        for (int ks = 0; ks < 8; ++ks) {
            const s16x8 ah = *(const s16x8*)&fc2h[(chb + li)*256 + 32*ks + 8*g];
            const s16x8 al = *(const s16x8*)&fc2l[(chb + li)*256 + 32*ks + 8*g];
            const s16x8 bh0 = *(const s16x8*)&chH[((4*ks + g)*32 + li) * 8];
            const s16x8 bl0 = *(const s16x8*)&chL[((4*ks + g)*32 + li) * 8];
            const s16x8 bh1 = *(const s16x8*)&chH[((4*ks + g)*32 + 16 + li) * 8];
            const s16x8 bl1 = *(const s16x8*)&chL[((4*ks + g)*32 + 16 + li) * 8];
            accA = MFMA(al, bh0, accA);
            accA = MFMA(ah, bl0, accA);
            accA = MFMA(ah, bh0, accA);
            accB = MFMA(al, bh1, accB);
            accB = MFMA(ah, bl1, accB);
            accB = MFMA(ah, bh1, accB);
        }
        const float4 bb = *(const float4*)&fc2b[chb + 4*g];
        {
            const int tok = base + li;
            float4 res = *(const float4*)&xout[(size_t)tok*DIMC + chb + 4*g];
            float4 o;
            o.x = res.x + accA[0] + bb.x;
            o.y = res.y + accA[1] + bb.y;
            o.z = res.z + accA[2] + bb.z;
            o.w = res.w + accA[3] + bb.w;
            *(float4*)&xout[(size_t)tok*DIMC + chb + 4*g] = o;
        }
        {
            const int tok = base + 16 + li;
            float4 res = *(const float4*)&xout[(size_t)tok*DIMC + chb + 4*g];
            float4 o;
            o.x = res.x + accB[0] + bb.x;
            o.y = res.y + accB[1] + bb.y;
            o.z = res.z + accB[2] + bb.z;
            o.w = res.w + accB[3] + bb.w;
            *(float4*)&xout[(size_t)tok*DIMC + chb + 4*g] = o;
        }
    }
}

// ---------------------------------------------------------------------------
extern "C" void kernel_launch(void* const* d_in, const int* in_sizes, int n_in,
                              void* d_out, int out_size, void* d_ws, size_t ws_size,
                              hipStream_t stream)
{
    const float* x    = (const float*)d_in[0];
    const float* f    = (const float*)d_in[1];
    const float* n1w  = (const float*)d_in[2];
    const float* n1b  = (const float*)d_in[3];
    const float* n1fw = (const float*)d_in[4];
    const float* n1fb = (const float*)d_in[5];
    const float* wqx  = (const float*)d_in[6];
    const float* bqx  = (const float*)d_in[7];
    const float* wkvx = (const float*)d_in[8];
    const float* bkvx = (const float*)d_in[9];
    const float* wqf  = (const float*)d_in[10];
    const float* bqf  = (const float*)d_in[11];
    const float* wkvf = (const float*)d_in[12];
    const float* bkvf = (const float*)d_in[13];
    const float* rpb  = (const float*)d_in[14];
    const float* projw= (const float*)d_in[15];
    const float* projb= (const float*)d_in[16];
    const float* n2w  = (const float*)d_in[17];
    const float* n2b  = (const float*)d_in[18];
    const float* fc1w = (const float*)d_in[19];
    const float* fc1b = (const float*)d_in[20];
    const float* cw   = (const float*)d_in[21];
    const float* cb   = (const float*)d_in[22];
    const float* fc2w = (const float*)d_in[23];
    const float* fc2b = (const float*)d_in[24];
    float* out = (float*)d_out;

    // Layout: y1 in ws (128 MiB); tables after it; xmid lives in d_out.
    bfu* y1 = (bfu*)d_ws;
    char* tb = (char*)d_ws + (size_t)LTOK * HIDC * 2;
    ushort* wb   = (ushort*)tb;                 // 114688 ushorts = 224 KiB
    float* bsc   = (float*)(tb + 229376);       // 128 f32
    float* bias2 = (float*)(tb + 229888);       // 8192 f32
    float* xmid  = out;                         // d_out doubles as xmid scratch

    hipLaunchKernelGGL(k_prep, dim3(353), dim3(256), 0, stream,
                       wqx, wkvx, wqf, wkvf, projw, bqx, bqf, rpb, fc1w, fc2w,
                       wb, bsc, bias2);
    hipLaunchKernelGGL(k_attn, dim3(NWIN), dim3(512), 0, stream,
                       x, f, n1w, n1b, n1fw, n1fb, bkvx, bkvf, projw, projb,
                       n2w, n2b, wb + 49152, wb + 65536, fc1b,
                       wb, bsc, bias2, xmid, y1);
    hipLaunchKernelGGL(k_conv_fc2, dim3(LTOK/32), dim3(256), 0, stream,
                       y1, cw, cb, wb + 81920, wb + 98304, fc2b, xmid);
}

// Round 15
// 520.486 us; speedup vs baseline: 1.0653x; 1.0653x over previous
//
#include <hip/hip_runtime.h>

#define RES  512
#define LTOK (RES*RES)
#define DIMC 64
#define HIDC 256
#define NWIN 4096

typedef unsigned short bfu;
typedef __attribute__((ext_vector_type(8))) short s16x8;
typedef __attribute__((ext_vector_type(4))) float f32x4;

#define MFMA(a,b,c) __builtin_amdgcn_mfma_f32_16x16x32_bf16((a),(b),(c),0,0,0)

__device__ inline bfu f2bf(float f) {
    unsigned b = __float_as_uint(f);
    return (bfu)((b + 0x7FFFu + ((b >> 16) & 1u)) >> 16);
}
__device__ inline float bf2f(bfu u) { return __uint_as_float((unsigned)u << 16); }
__device__ inline ushort4 pack4(float a, float b, float c, float d) {
    ushort4 r; r.x = f2bf(a); r.y = f2bf(b); r.z = f2bf(c); r.w = f2bf(d); return r;
}

// Chunked fragment layout for 64x64 bf16 matrix M[row][k]:
//   element (row,k) at ushort index ((k>>3)*64 + row)*8 + (k&7)
__device__ inline s16x8 fldl(const ushort* buf, int chunkbase, int rowbase, int g, int li) {
    return *(const s16x8*)&buf[((chunkbase + g) * 64 + rowbase + li) * 8];
}
__device__ inline s16x8 fldg(const ushort* w, int rowbase, int ks, int g, int li) {
    return *(const s16x8*)&w[(rowbase + li) * 64 + 32 * ks + 8 * g];
}

// LayerNorm, 512-thread version: 8 lanes per token, 8 channels each.
__device__ inline void ln_win512(const float* __restrict__ src,
                                 const float* __restrict__ lw, const float* __restrict__ lb,
                                 ushort* dsth, ushort* dstl, int wi, int wj, int tid)
{
    const int n = tid >> 3, p = tid & 7;
    const int gtok = (wi * 8 + (n >> 3)) * RES + wj * 8 + (n & 7);
    const float* rp = src + (size_t)gtok * DIMC + p * 8;
    float v[8];
    *(float4*)&v[0] = *(const float4*)&rp[0];
    *(float4*)&v[4] = *(const float4*)&rp[4];
    float s = 0.f, s2 = 0.f;
    #pragma unroll
    for (int j = 0; j < 8; ++j) { s += v[j]; s2 += v[j] * v[j]; }
    s  += __shfl_xor(s, 1);  s  += __shfl_xor(s, 2);  s  += __shfl_xor(s, 4);
    s2 += __shfl_xor(s2, 1); s2 += __shfl_xor(s2, 2); s2 += __shfl_xor(s2, 4);
    const float mean = s * 0.015625f;
    const float var  = s2 * 0.015625f - mean * mean;
    const float rs = rsqrtf(var + 1e-5f);
    float wv[8], bv[8];
    *(float4*)&wv[0] = *(const float4*)&lw[p*8+0];  *(float4*)&bv[0] = *(const float4*)&lb[p*8+0];
    *(float4*)&wv[4] = *(const float4*)&lw[p*8+4];  *(float4*)&bv[4] = *(const float4*)&lb[p*8+4];
    unsigned pkh[4], pkl[4];
    #pragma unroll
    for (int j = 0; j < 4; ++j) {
        float a = (v[2*j]   - mean) * rs * wv[2*j]   + bv[2*j];
        float b = (v[2*j+1] - mean) * rs * wv[2*j+1] + bv[2*j+1];
        bfu ha = f2bf(a), hb = f2bf(b);
        bfu la = f2bf(a - bf2f(ha)), lb2 = f2bf(b - bf2f(hb));
        pkh[j] = (unsigned)ha | ((unsigned)hb << 16);
        pkl[j] = (unsigned)la | ((unsigned)lb2 << 16);
    }
    *(int4*)&dsth[(p * 64 + n) * 8] = *(const int4*)&pkh[0];
    *(int4*)&dstl[(p * 64 + n) * 8] = *(const int4*)&pkl[0];
}

// LayerNorm (sequential tokens, 256-thread) -> hi/lo chunked (for k_fc1)
__device__ inline void ln_seq2(const float* __restrict__ src,
                               const float* __restrict__ lw, const float* __restrict__ lb,
                               ushort* dsth, ushort* dstl, int base, int tid)
{
    const int n = tid >> 2, p = tid & 3;
    const int gtok = base + n;
    const float* rp = src + (size_t)gtok * DIMC + p * 16;
    float v[16];
    *(float4*)&v[0]  = *(const float4*)&rp[0];
    *(float4*)&v[4]  = *(const float4*)&rp[4];
    *(float4*)&v[8]  = *(const float4*)&rp[8];
    *(float4*)&v[12] = *(const float4*)&rp[12];
    float s = 0.f, s2 = 0.f;
    #pragma unroll
    for (int j = 0; j < 16; ++j) { s += v[j]; s2 += v[j] * v[j]; }
    s  += __shfl_xor(s, 1);  s  += __shfl_xor(s, 2);
    s2 += __shfl_xor(s2, 1); s2 += __shfl_xor(s2, 2);
    const float mean = s * 0.015625f;
    const float var  = s2 * 0.015625f - mean * mean;
    const float rs = rsqrtf(var + 1e-5f);
    float wv[16], bv[16];
    *(float4*)&wv[0]  = *(const float4*)&lw[p*16+0];  *(float4*)&bv[0]  = *(const float4*)&lb[p*16+0];
    *(float4*)&wv[4]  = *(const float4*)&lw[p*16+4];  *(float4*)&bv[4]  = *(const float4*)&lb[p*16+4];
    *(float4*)&wv[8]  = *(const float4*)&lw[p*16+8];  *(float4*)&bv[8]  = *(const float4*)&lb[p*16+8];
    *(float4*)&wv[12] = *(const float4*)&lw[p*16+12]; *(float4*)&bv[12] = *(const float4*)&lb[p*16+12];
    unsigned pkh[8], pkl[8];
    #pragma unroll
    for (int j = 0; j < 8; ++j) {
        float a = (v[2*j]   - mean) * rs * wv[2*j]   + bv[2*j];
        float b = (v[2*j+1] - mean) * rs * wv[2*j+1] + bv[2*j+1];
        bfu ha = f2bf(a), hb = f2bf(b);
        bfu la = f2bf(a - bf2f(ha)), lb2 = f2bf(b - bf2f(hb));
        pkh[j] = (unsigned)ha | ((unsigned)hb << 16);
        pkl[j] = (unsigned)la | ((unsigned)lb2 << 16);
    }
    *(int4*)&dsth[((2*p)   * 64 + n) * 8] = *(const int4*)&pkh[0];
    *(int4*)&dsth[((2*p+1) * 64 + n) * 8] = *(const int4*)&pkh[4];
    *(int4*)&dstl[((2*p)   * 64 + n) * 8] = *(const int4*)&pkl[0];
    *(int4*)&dstl[((2*p+1) * 64 + n) * 8] = *(const int4*)&pkl[4];
}

// Split-precision transposed projection, HALF version: ct in {2cth, 2cth+1}.
__device__ inline void gemmT3h(const ushort* __restrict__ wTh, const ushort* __restrict__ wTl,
                               const ushort* xh, const ushort* xl,
                               const float* __restrict__ biasv,
                               ushort* dst, int w, int cth, int g, int li)
{
    const s16x8 ah0 = fldg(wTh, 16*w, 0, g, li);
    const s16x8 ah1 = fldg(wTh, 16*w, 1, g, li);
    const s16x8 al0 = fldg(wTl, 16*w, 0, g, li);
    const s16x8 al1 = fldg(wTl, 16*w, 1, g, li);
    const float4 bias = *(const float4*)&biasv[16*w + 4*g];
    #pragma unroll
    for (int c2 = 0; c2 < 2; ++c2) {
        const int ct = 2*cth + c2;
        const s16x8 bh0 = fldl(xh, 0, 16*ct, g, li);
        const s16x8 bh1 = fldl(xh, 4, 16*ct, g, li);
        const s16x8 bl0 = fldl(xl, 0, 16*ct, g, li);
        const s16x8 bl1 = fldl(xl, 4, 16*ct, g, li);
        f32x4 acc = {0.f, 0.f, 0.f, 0.f};
        acc = MFMA(al0, bh0, acc);
        acc = MFMA(al1, bh1, acc);
        acc = MFMA(ah0, bl0, acc);
        acc = MFMA(ah1, bl1, acc);
        acc = MFMA(ah0, bh0, acc);
        acc = MFMA(ah1, bh1, acc);
        *(ushort4*)&dst[((2*w + (g>>1)) * 64 + 16*ct + li) * 8 + (g&1)*4] =
            pack4(acc[0]+bias.x, acc[1]+bias.y, acc[2]+bias.z, acc[3]+bias.w);
    }
}

// HALF version, f32 store (stride 68): token = 16ct+li, channel = 16w+4g+r.
__device__ inline void gemmT3fh(const ushort* __restrict__ wTh, const ushort* __restrict__ wTl,
                                const ushort* xh, const ushort* xl,
                                const float* __restrict__ biasv,
                                float* dst, int w, int cth, int g, int li)
{
    const s16x8 ah0 = fldg(wTh, 16*w, 0, g, li);
    const s16x8 ah1 = fldg(wTh, 16*w, 1, g, li);
    const s16x8 al0 = fldg(wTl, 16*w, 0, g, li);
    const s16x8 al1 = fldg(wTl, 16*w, 1, g, li);
    const float4 bias = *(const float4*)&biasv[16*w + 4*g];
    #pragma unroll
    for (int c2 = 0; c2 < 2; ++c2) {
        const int ct = 2*cth + c2;
        const s16x8 bh0 = fldl(xh, 0, 16*ct, g, li);
        const s16x8 bh1 = fldl(xh, 4, 16*ct, g, li);
        const s16x8 bl0 = fldl(xl, 0, 16*ct, g, li);
        const s16x8 bl1 = fldl(xl, 4, 16*ct, g, li);
        f32x4 acc = {0.f, 0.f, 0.f, 0.f};
        acc = MFMA(al0, bh0, acc);
        acc = MFMA(al1, bh1, acc);
        acc = MFMA(ah0, bl0, acc);
        acc = MFMA(ah1, bl1, acc);
        acc = MFMA(ah0, bh0, acc);
        acc = MFMA(ah1, bh1, acc);
        float4 st = { acc[0]+bias.x, acc[1]+bias.y, acc[2]+bias.z, acc[3]+bias.w };
        *(float4*)&dst[(16*ct + li)*68 + 16*w + 4*g] = st;
    }
}

// Full version (256-thread kernels), bf16 chunked store.
__device__ inline void gemmT3(const ushort* __restrict__ wTh, const ushort* __restrict__ wTl,
                              const ushort* xh, const ushort* xl,
                              const float* __restrict__ biasv,
                              ushort* dst, int w, int g, int li)
{
    const s16x8 ah0 = fldg(wTh, 16*w, 0, g, li);
    const s16x8 ah1 = fldg(wTh, 16*w, 1, g, li);
    const s16x8 al0 = fldg(wTl, 16*w, 0, g, li);
    const s16x8 al1 = fldg(wTl, 16*w, 1, g, li);
    const float4 bias = *(const float4*)&biasv[16*w + 4*g];
    #pragma unroll
    for (int ct = 0; ct < 4; ++ct) {
        const s16x8 bh0 = fldl(xh, 0, 16*ct, g, li);
        const s16x8 bh1 = fldl(xh, 4, 16*ct, g, li);
        const s16x8 bl0 = fldl(xl, 0, 16*ct, g, li);
        const s16x8 bl1 = fldl(xl, 4, 16*ct, g, li);
        f32x4 acc = {0.f, 0.f, 0.f, 0.f};
        acc = MFMA(al0, bh0, acc);
        acc = MFMA(al1, bh1, acc);
        acc = MFMA(ah0, bl0, acc);
        acc = MFMA(ah1, bl1, acc);
        acc = MFMA(ah0, bh0, acc);
        acc = MFMA(ah1, bh1, acc);
        *(ushort4*)&dst[((2*w + (g>>1)) * 64 + 16*ct + li) * 8 + (g&1)*4] =
            pack4(acc[0]+bias.x, acc[1]+bias.y, acc[2]+bias.z, acc[3]+bias.w);
    }
}

// ---------------------------------------------------------------------------
// Prep: attn tables (12 matrices, bsc, bias2) + fc1/fc2 transposed hi/lo.
// ---------------------------------------------------------------------------
__global__ __launch_bounds__(256) void k_prep(
    const float* __restrict__ wqx, const float* __restrict__ wkvx,
    const float* __restrict__ wqf, const float* __restrict__ wkvf,
    const float* __restrict__ projw, const float* __restrict__ bqx,
    const float* __restrict__ bqf, const float* __restrict__ rpb,
    const float* __restrict__ fc1w, const float* __restrict__ fc2w,
    ushort* __restrict__ wb, float* __restrict__ bsc, float* __restrict__ bias2)
{
    const float scale = 0.17677669529663687f;  // 32^-0.5
    int t = blockIdx.x * 256 + threadIdx.x;
    if (t < 49152) {
        int m = t >> 12, idx = t & 4095;
        int c = idx >> 6, k = idx & 63;
        int mm = m % 6;
        float val;
        switch (mm) {
            case 0:  val = wqx [k*64  + c] * scale; break;
            case 1:  val = wkvx[k*128 + c];         break;
            case 2:  val = wkvx[k*128 + 64 + c];    break;
            case 3:  val = wqf [k*64  + c] * scale; break;
            case 4:  val = wkvf[k*128 + c];         break;
            default: val = projw[k*64 + c];         break;
        }
        bfu h = f2bf(val);
        wb[m*4096 + c*64 + k] = (m < 6) ? h : f2bf(val - bf2f(h));
    } else if (t < 65536) {            // fc1^T hi+lo: [256 out][64 k]
        int i = t - 49152;
        int c = i >> 6, k = i & 63;
        float val = fc1w[k*HIDC + c];
        bfu h = f2bf(val);
        wb[49152 + i] = h;
        wb[65536 + i] = f2bf(val - bf2f(h));
    } else if (t < 81920) {            // fc2^T hi+lo: [64 out][256 k]
        int i = t - 65536;
        int c = i >> 8, k = i & 255;
        float val = fc2w[k*DIMC + c];
        bfu h = f2bf(val);
        wb[81920 + i] = h;
        wb[98304 + i] = f2bf(val - bf2f(h));
    } else if (t < 82048) {
        int i = t - 81920;
        bsc[i] = (i < 64) ? bqx[i] * scale : bqf[i-64] * scale;
    } else if (t < 90240) {
        int i = t - 82048;
        int h = i >> 12, rest = i & 4095;
        int n = rest >> 6, m2 = rest & 63;
        int idx = ((n>>3) - (m2>>3) + 7) * 15 + ((n&7) - (m2&7) + 7);
        bias2[h*4096 + rest] = rpb[idx*2 + h];
    }
}

// ---------------------------------------------------------------------------
// Kernel A (R13, bit-proven): 512 threads / window.
// ---------------------------------------------------------------------------
__global__ __launch_bounds__(512, 4) void k_attn(
    const float* __restrict__ x, const float* __restrict__ f,
    const float* __restrict__ n1w, const float* __restrict__ n1b,
    const float* __restrict__ n1fw, const float* __restrict__ n1fb,
    const float* __restrict__ bkvx, const float* __restrict__ bkvf,
    const float* __restrict__ projw32, const float* __restrict__ projb,
    const ushort* __restrict__ wbufs, const float* __restrict__ bsc,
    const float* __restrict__ bias2,
    float* __restrict__ xmid)
{
    __shared__ __align__(16) unsigned char LDSRAW[75776];
    ushort* bufA   = (ushort*)(LDSRAW);
    ushort* bufAlo = (ushort*)(LDSRAW + 8192);
    ushort* bufQF  = (ushort*)(LDSRAW + 16384);
    ushort* bufKF  = (ushort*)(LDSRAW + 24576);
    ushort* bufQ   = (ushort*)(LDSRAW + 32768);
    float*  Kf32   = (float*)(LDSRAW + 40960);
    float*  Vf32   = (float*)(LDSRAW + 58368);
    float*  Pf     = (float*)(LDSRAW);            // [2][64][65]
    float*  Of     = (float*)(LDSRAW + 33280);    // [64][68]
    float*  Wlds   = (float*)(LDSRAW);            // [64][68] after Ph5

    const int tid = (int)threadIdx.x;
    const int wv = tid >> 6, lane = tid & 63, g = lane >> 4, li = lane & 15;
    const int wid = blockIdx.x, wi = wid >> 6, wj = wid & 63;
    const int w8 = wv & 3, cth = wv >> 2;         // gemm split

    const ushort* wqxTh  = wbufs;
    const ushort* wkxTh  = wbufs + 4096;
    const ushort* wvxTh  = wbufs + 8192;
    const ushort* wqfTh  = wbufs + 12288;
    const ushort* wkfTh  = wbufs + 16384;
    const ushort* wqxTl  = wbufs + 24576;
    const ushort* wkxTl  = wbufs + 28672;
    const ushort* wvxTl  = wbufs + 32768;
    const ushort* wqfTl  = wbufs + 36864;
    const ushort* wkfTl  = wbufs + 40960;
    const float* bqxs = bsc, * bqfs = bsc + 64;

    // Ph0: LN(f) -> A(hi), Alo(lo)
    ln_win512(f, n1fw, n1fb, bufA, bufAlo, wi, wj, tid);
    __syncthreads();

    // Ph1: qf -> QF, kf -> KF (each wave does half of each gemm)
    gemmT3h(wqfTh, wqfTl, bufA, bufAlo, bqfs, bufQF, w8, cth, g, li);
    gemmT3h(wkfTh, wkfTl, bufA, bufAlo, bkvf, bufKF, w8, cth, g, li);
    __syncthreads();

    // Ph2: LN(x) -> A/Alo (fn dead)
    ln_win512(x, n1w, n1b, bufA, bufAlo, wi, wj, tid);
    __syncthreads();

    // Ph3: q -> Q (bf16), k -> Kf32, v -> Vf32
    gemmT3h (wqxTh, wqxTl, bufA, bufAlo, bqxs,      bufQ, w8, cth, g, li);
    gemmT3fh(wkxTh, wkxTl, bufA, bufAlo, bkvx,      Kf32, w8, cth, g, li);
    gemmT3fh(wvxTh, wvxTl, bufA, bufAlo, bkvx + 64, Vf32, w8, cth, g, li);
    __syncthreads();

    // Ph4: fused S_f + S_x + joint logits + softmax, all in registers.
    const int h2 = tid >> 8, q2 = (tid >> 2) & 63, kh = tid & 3;
    float p[16];
    float den;
    {
        float qfreg[32], qreg[32];
        #pragma unroll
        for (int cc = 0; cc < 4; ++cc) {
            const s16x8 qfv = *(const s16x8*)&bufQF[((4*h2+cc)*64 + q2)*8];
            const s16x8 qv  = *(const s16x8*)&bufQ [((4*h2+cc)*64 + q2)*8];
            #pragma unroll
            for (int j = 0; j < 8; ++j) {
                qfreg[8*cc+j] = bf2f((bfu)(unsigned short)qfv[j]);
                qreg [8*cc+j] = bf2f((bfu)(unsigned short)qv[j]);
            }
        }
        const float* brow = &bias2[h2*4096 + q2*64];
        float mx = -1e30f;
        #pragma unroll
        for (int mi = 0; mi < 16; ++mi) {
            const int m = 4*mi + kh;
            float sf = 0.f, sx = 0.f;
            #pragma unroll
            for (int cc = 0; cc < 4; ++cc) {
                const s16x8 kfv = *(const s16x8*)&bufKF[((4*h2+cc)*64 + m)*8];
                #pragma unroll
                for (int j = 0; j < 8; ++j) sf += qfreg[8*cc+j] * bf2f((bfu)(unsigned short)kfv[j]);
            }
            #pragma unroll
            for (int c4 = 0; c4 < 8; ++c4) {
                const float4 kv = *(const float4*)&Kf32[m*68 + 32*h2 + 4*c4];
                sx += qreg[4*c4+0]*kv.x + qreg[4*c4+1]*kv.y
                    + qreg[4*c4+2]*kv.z + qreg[4*c4+3]*kv.w;
            }
            const float b = brow[m];
            const float lv = (sx + b) * (sf + b);
            p[mi] = lv;
            mx = fmaxf(mx, lv);
        }
        mx = fmaxf(mx, __shfl_xor(mx, 1));
        mx = fmaxf(mx, __shfl_xor(mx, 2));
        den = 0.f;
        #pragma unroll
        for (int mi = 0; mi < 16; ++mi) {
            const float e = __expf(p[mi] - mx);
            p[mi] = e;
            den += e;
        }
        den += __shfl_xor(den, 1);
        den += __shfl_xor(den, 2);
    }
    __syncthreads();   // q/qf/kf/K reads complete; P may overwrite

    // Ph4b: P (f32, stride 65) -> Pf; den -> row slot 64
    {
        float* srow = &Pf[h2*4160 + q2*65];
        #pragma unroll
        for (int mi = 0; mi < 16; ++mi) srow[4*mi + kh] = p[mi];
        if (kh == 0) srow[64] = den;
    }
    __syncthreads();

    // Ph5: PV (f32). wave -> (head, channel-octet); lane = query
    {
        const int comp = wv;
        const int head = comp >> 2, quarter = comp & 3;
        const int cbase = head*32 + quarter*8;
        const int n2 = lane;
        float acc[8];
        #pragma unroll
        for (int j = 0; j < 8; ++j) acc[j] = 0.f;
        const float* prow = &Pf[head*4160 + n2*65];
        for (int m = 0; m < 64; ++m) {
            const float pv = prow[m];
            #pragma unroll
            for (int c4 = 0; c4 < 2; ++c4) {
                const float4 vv = *(const float4*)&Vf32[m*68 + cbase + 4*c4];
                acc[4*c4+0] += pv * vv.x;
                acc[4*c4+1] += pv * vv.y;
                acc[4*c4+2] += pv * vv.z;
                acc[4*c4+3] += pv * vv.w;
            }
        }
        const float inv = 1.f / prow[64];
        #pragma unroll
        for (int j4 = 0; j4 < 2; ++j4) {
            float4 st = { acc[4*j4]*inv, acc[4*j4+1]*inv, acc[4*j4+2]*inv, acc[4*j4+3]*inv };
            *(float4*)&Of[n2*68 + cbase + 4*j4] = st;
        }
    }
    __syncthreads();   // P dead; W may overwrite

    // Ph5c: stage projw -> Wlds [64][68] (L2-hot 16KB, coalesced)
    {
        const int row = tid >> 3, c = (tid & 7) * 8;
        const float4 w0 = *(const float4*)&projw32[row*64 + c];
        const float4 w1 = *(const float4*)&projw32[row*64 + c + 4];
        *(float4*)&Wlds[row*68 + c]     = w0;
        *(float4*)&Wlds[row*68 + c + 4] = w1;
    }
    __syncthreads();

    // Ph6: proj from LDS + bias + residual -> xmid. thread = (token, 8-ch group)
    {
        const int n = tid >> 3, c0q = (tid & 7) * 8;
        float acc2[8];
        *(float4*)&acc2[0] = *(const float4*)&projb[c0q];
        *(float4*)&acc2[4] = *(const float4*)&projb[c0q + 4];
        for (int kk = 0; kk < 64; ++kk) {
            const float a = Of[n*68 + kk];
            const float* wr = Wlds + kk*68 + c0q;
            #pragma unroll
            for (int j = 0; j < 8; ++j) acc2[j] += a * wr[j];
        }
        const int gtok = (wi*8 + (n >> 3)) * RES + wj*8 + (n & 7);
        const float4 r0 = *(const float4*)&x[(size_t)gtok*DIMC + c0q];
        const float4 r1 = *(const float4*)&x[(size_t)gtok*DIMC + c0q + 4];
        float4 o0 = { acc2[0]+r0.x, acc2[1]+r0.y, acc2[2]+r0.z, acc2[3]+r0.w };
        float4 o1 = { acc2[4]+r1.x, acc2[5]+r1.y, acc2[6]+r1.z, acc2[7]+r1.w };
        *(float4*)&xmid[(size_t)gtok*DIMC + c0q]     = o0;
        *(float4*)&xmid[(size_t)gtok*DIMC + c0q + 4] = o1;
    }
}

// ---------------------------------------------------------------------------
// Kernel B (MFMA): LN(xmid) -> fc1 (split-precision) -> y1 (bf16).
// ---------------------------------------------------------------------------
__global__ __launch_bounds__(256) void k_fc1(
    const float* __restrict__ xm,
    const float* __restrict__ n2w, const float* __restrict__ n2b,
    const ushort* __restrict__ fc1h, const ushort* __restrict__ fc1l,
    const float* __restrict__ fc1b,
    bfu* __restrict__ y1)
{
    __shared__ __align__(16) ushort xh[4096], xl[4096];
    const int tid = (int)threadIdx.x, wv = tid >> 6, lane = tid & 63;
    const int g = lane >> 4, li = lane & 15;
    const int base = blockIdx.x * 64;

    ln_seq2(xm, n2w, n2b, xh, xl, base, tid);
    __syncthreads();

    #pragma unroll
    for (int ot = 0; ot < 4; ++ot) {
        const int chb = 64*wv + 16*ot;
        const s16x8 ah0 = fldg(fc1h, chb, 0, g, li);
        const s16x8 ah1 = fldg(fc1h, chb, 1, g, li);
        const s16x8 al0 = fldg(fc1l, chb, 0, g, li);
        const s16x8 al1 = fldg(fc1l, chb, 1, g, li);
        const float4 bb = *(const float4*)&fc1b[chb + 4*g];
        #pragma unroll
        for (int ct = 0; ct < 4; ++ct) {
            const s16x8 bh0 = fldl(xh, 0, 16*ct, g, li);
            const s16x8 bh1 = fldl(xh, 4, 16*ct, g, li);
            const s16x8 bl0 = fldl(xl, 0, 16*ct, g, li);
            const s16x8 bl1 = fldl(xl, 4, 16*ct, g, li);
            f32x4 acc = {0.f, 0.f, 0.f, 0.f};
            acc = MFMA(al0, bh0, acc);
            acc = MFMA(al1, bh1, acc);
            acc = MFMA(ah0, bl0, acc);
            acc = MFMA(ah1, bl1, acc);
            acc = MFMA(ah0, bh0, acc);
            acc = MFMA(ah1, bh1, acc);
            const int tok = base + 16*ct + li;
            *(ushort4*)&y1[(size_t)tok*HIDC + chb + 4*g] =
                pack4(acc[0]+bb.x, acc[1]+bb.y, acc[2]+bb.z, acc[3]+bb.w);
        }
    }
}

// ---------------------------------------------------------------------------
// Kernel C: depthwise 3x3 conv + relu (VALU, sliding-column reuse) ->
// fc2 (split-MFMA, K=256) + bias + residual, in-place on d_out.
// Block = 32 tokens (always within one image row).
// ---------------------------------------------------------------------------
__global__ __launch_bounds__(256) void k_conv_fc2(
    const bfu* __restrict__ y1,
    const float* __restrict__ cw, const float* __restrict__ cb,
    const ushort* __restrict__ fc2h, const ushort* __restrict__ fc2l,
    const float* __restrict__ fc2b,
    float* __restrict__ xout)
{
    __shared__ float scw[2304];
    __shared__ __align__(16) ushort chH[8192], chL[8192];  // [32 tok][256 ch] chunked
    const int tid = (int)threadIdx.x, wv = tid >> 6, lane = tid & 63;
    const int g = lane >> 4, li = lane & 15;

    for (int i = tid; i < 2304; i += 256) scw[i] = cw[i];
    __syncthreads();

    const int base = blockIdx.x * 32;
    const int ch0 = lane * 4;

    float kw[4][9];
    #pragma unroll
    for (int j = 0; j < 4; ++j)
        #pragma unroll
        for (int kidx = 0; kidx < 9; ++kidx) kw[j][kidx] = scw[(ch0+j)*9 + kidx];
    const float cb0 = cb[ch0], cb1 = cb[ch0+1], cb2 = cb[ch0+2], cb3 = cb[ch0+3];

    // Sliding-column 3x3 conv: thread owns 8 consecutive-w tokens of one row.
    const int hh = base >> 9;                    // image row (same for block)
    const int wbase = (base & 511) + wv * 8;     // first w for this thread
    const bool rup = (hh > 0), rdn = (hh < RES - 1);

    float c0[12], c1[12], c2[12];   // [row 0..2][ch 0..3]; rows: hh-1, hh, hh+1
    // column loader: zero-fill out-of-range rows/cols (adds +0.0 -> exact)
    #define LOADCOL(w2, C) do {                                              \
        if ((w2) < 0 || (w2) >= RES) {                                       \
            _Pragma("unroll") for (int j = 0; j < 12; ++j) (C)[j] = 0.f;     \
        } else {                                                             \
            if (rup) { const ushort4 u = *(const ushort4*)&y1[(size_t)((hh-1)*RES + (w2))*HIDC + ch0]; \
                (C)[0]=bf2f(u.x); (C)[1]=bf2f(u.y); (C)[2]=bf2f(u.z); (C)[3]=bf2f(u.w); } \
            else { (C)[0]=0.f; (C)[1]=0.f; (C)[2]=0.f; (C)[3]=0.f; }         \
            { const ushort4 u = *(const ushort4*)&y1[(size_t)(hh*RES + (w2))*HIDC + ch0]; \
                (C)[4]=bf2f(u.x); (C)[5]=bf2f(u.y); (C)[6]=bf2f(u.z); (C)[7]=bf2f(u.w); } \
            if (rdn) { const ushort4 u = *(const ushort4*)&y1[(size_t)((hh+1)*RES + (w2))*HIDC + ch0]; \
                (C)[8]=bf2f(u.x); (C)[9]=bf2f(u.y); (C)[10]=bf2f(u.z); (C)[11]=bf2f(u.w); } \
            else { (C)[8]=0.f; (C)[9]=0.f; (C)[10]=0.f; (C)[11]=0.f; }       \
        } } while (0)

    LOADCOL(wbase - 1, c0);
    LOADCOL(wbase,     c1);

    #pragma unroll
    for (int t = 0; t < 8; ++t) {
        LOADCOL(wbase + t + 1, c2);
        float a0 = cb0, a1 = cb1, a2 = cb2, a3 = cb3;
        // reference tap order: dh outer (-1,0,1), dw inner (-1,0,1)
        #pragma unroll
        for (int dh = 0; dh < 3; ++dh) {
            a0 += c0[dh*4+0]*kw[0][dh*3+0]; a1 += c0[dh*4+1]*kw[1][dh*3+0];
            a2 += c0[dh*4+2]*kw[2][dh*3+0]; a3 += c0[dh*4+3]*kw[3][dh*3+0];
            a0 += c1[dh*4+0]*kw[0][dh*3+1]; a1 += c1[dh*4+1]*kw[1][dh*3+1];
            a2 += c1[dh*4+2]*kw[2][dh*3+1]; a3 += c1[dh*4+3]*kw[3][dh*3+1];
            a0 += c2[dh*4+0]*kw[0][dh*3+2]; a1 += c2[dh*4+1]*kw[1][dh*3+2];
            a2 += c2[dh*4+2]*kw[2][dh*3+2]; a3 += c2[dh*4+3]*kw[3][dh*3+2];
        }
        a0 = fmaxf(a0, 0.f); a1 = fmaxf(a1, 0.f);
        a2 = fmaxf(a2, 0.f); a3 = fmaxf(a3, 0.f);
        ushort4 hi, lo;
        hi.x = f2bf(a0); lo.x = f2bf(a0 - bf2f(hi.x));
        hi.y = f2bf(a1); lo.y = f2bf(a1 - bf2f(hi.y));
        hi.z = f2bf(a2); lo.z = f2bf(a2 - bf2f(hi.z));
        hi.w = f2bf(a3); lo.w = f2bf(a3 - bf2f(hi.w));
        const int tr = wv * 8 + t;
        const int cidx = ((ch0 >> 3) * 32 + tr) * 8 + (ch0 & 7);
        *(ushort4*)&chH[cidx] = hi;
        *(ushort4*)&chL[cidx] = lo;
        // rotate columns (static indices)
        #pragma unroll
        for (int j = 0; j < 12; ++j) { c0[j] = c1[j]; c1[j] = c2[j]; }
    }
    #undef LOADCOL
    __syncthreads();

    // fc2: wave wv -> out-channel tile 16*wv; K=256 (8 k-steps x 3 split terms)
    {
        const int chb = 16 * wv;
        f32x4 accA = {0.f, 0.f, 0.f, 0.f};
        f32x4 accB = {0.f, 0.f, 0.f, 0.f};
        #pragma unroll
        for (int ks = 0; ks < 8; ++ks) {
            const s16x8 ah = *(const s16x8*)&fc2h[(chb + li)*256 + 32*ks + 8*g];
            const s16x8 al = *(const s16x8*)&fc2l[(chb + li)*256 + 32*ks + 8*g];
            const s16x8 bh0 = *(const s16x8*)&chH[((4*ks + g)*32 + li) * 8];
            const s16x8 bl0 = *(const s16x8*)&chL[((4*ks + g)*32 + li) * 8];
            const s16x8 bh1 = *(const s16x8*)&chH[((4*ks + g)*32 + 16 + li) * 8];
            const s16x8 bl1 = *(const s16x8*)&chL[((4*ks + g)*32 + 16 + li) * 8];
            accA = MFMA(al, bh0, accA);
            accA = MFMA(ah, bl0, accA);
            accA = MFMA(ah, bh0, accA);
            accB = MFMA(al, bh1, accB);
            accB = MFMA(ah, bl1, accB);
            accB = MFMA(ah, bh1, accB);
        }
        const float4 bb = *(const float4*)&fc2b[chb + 4*g];
        {
            const int tok = base + li;
            float4 res = *(const float4*)&xout[(size_t)tok*DIMC + chb + 4*g];
            float4 o;
            o.x = res.x + accA[0] + bb.x;
            o.y = res.y + accA[1] + bb.y;
            o.z = res.z + accA[2] + bb.z;
            o.w = res.w + accA[3] + bb.w;
            *(float4*)&xout[(size_t)tok*DIMC + chb + 4*g] = o;
        }
        {
            const int tok = base + 16 + li;
            float4 res = *(const float4*)&xout[(size_t)tok*DIMC + chb + 4*g];
            float4 o;
            o.x = res.x + accB[0] + bb.x;
            o.y = res.y + accB[1] + bb.y;
            o.z = res.z + accB[2] + bb.z;
            o.w = res.w + accB[3] + bb.w;
            *(float4*)&xout[(size_t)tok*DIMC + chb + 4*g] = o;
        }
    }
}

// ---------------------------------------------------------------------------
extern "C" void kernel_launch(void* const* d_in, const int* in_sizes, int n_in,
                              void* d_out, int out_size, void* d_ws, size_t ws_size,
                              hipStream_t stream)
{
    const float* x    = (const float*)d_in[0];
    const float* f    = (const float*)d_in[1];
    const float* n1w  = (const float*)d_in[2];
    const float* n1b  = (const float*)d_in[3];
    const float* n1fw = (const float*)d_in[4];
    const float* n1fb = (const float*)d_in[5];
    const float* wqx  = (const float*)d_in[6];
    const float* bqx  = (const float*)d_in[7];
    const float* wkvx = (const float*)d_in[8];
    const float* bkvx = (const float*)d_in[9];
    const float* wqf  = (const float*)d_in[10];
    const float* bqf  = (const float*)d_in[11];
    const float* wkvf = (const float*)d_in[12];
    const float* bkvf = (const float*)d_in[13];
    const float* rpb  = (const float*)d_in[14];
    const float* projw= (const float*)d_in[15];
    const float* projb= (const float*)d_in[16];
    const float* n2w  = (const float*)d_in[17];
    const float* n2b  = (const float*)d_in[18];
    const float* fc1w = (const float*)d_in[19];
    const float* fc1b = (const float*)d_in[20];
    const float* cw   = (const float*)d_in[21];
    const float* cb   = (const float*)d_in[22];
    const float* fc2w = (const float*)d_in[23];
    const float* fc2b = (const float*)d_in[24];
    float* out = (float*)d_out;

    // Layout: y1 in ws (128 MiB); tables after it; xmid lives in d_out.
    bfu* y1 = (bfu*)d_ws;
    char* tb = (char*)d_ws + (size_t)LTOK * HIDC * 2;
    ushort* wb   = (ushort*)tb;                 // 114688 ushorts = 224 KiB
    float* bsc   = (float*)(tb + 229376);       // 128 f32
    float* bias2 = (float*)(tb + 229888);       // 8192 f32
    float* xmid  = out;                         // d_out doubles as xmid scratch

    hipLaunchKernelGGL(k_prep, dim3(353), dim3(256), 0, stream,
                       wqx, wkvx, wqf, wkvf, projw, bqx, bqf, rpb, fc1w, fc2w,
                       wb, bsc, bias2);
    hipLaunchKernelGGL(k_attn, dim3(NWIN), dim3(512), 0, stream,
                       x, f, n1w, n1b, n1fw, n1fb, bkvx, bkvf, projw, projb,
                       wb, bsc, bias2, xmid);
    hipLaunchKernelGGL(k_fc1, dim3(LTOK/64), dim3(256), 0, stream,
                       xmid, n2w, n2b, wb + 49152, wb + 65536, fc1b, y1);
    hipLaunchKernelGGL(k_conv_fc2, dim3(LTOK/32), dim3(256), 0, stream,
                       y1, cw, cb, wb + 81920, wb + 98304, fc2b, xmid);
}

// Round 16
// 494.689 us; speedup vs baseline: 1.1209x; 1.0521x over previous
//
#include <hip/hip_runtime.h>

#define RES  512
#define LTOK (RES*RES)
#define DIMC 64
#define HIDC 256
#define NWIN 4096

typedef unsigned short bfu;
typedef __attribute__((ext_vector_type(8))) short s16x8;
typedef __attribute__((ext_vector_type(4))) float f32x4;

#define MFMA(a,b,c) __builtin_amdgcn_mfma_f32_16x16x32_bf16((a),(b),(c),0,0,0)

__device__ inline bfu f2bf(float f) {
    unsigned b = __float_as_uint(f);
    return (bfu)((b + 0x7FFFu + ((b >> 16) & 1u)) >> 16);
}
__device__ inline float bf2f(bfu u) { return __uint_as_float((unsigned)u << 16); }
__device__ inline ushort4 pack4(float a, float b, float c, float d) {
    ushort4 r; r.x = f2bf(a); r.y = f2bf(b); r.z = f2bf(c); r.w = f2bf(d); return r;
}

// Chunked fragment layout for 64x64 bf16 matrix M[row][k]:
//   element (row,k) at ushort index ((k>>3)*64 + row)*8 + (k&7)
__device__ inline s16x8 fldl(const ushort* buf, int chunkbase, int rowbase, int g, int li) {
    return *(const s16x8*)&buf[((chunkbase + g) * 64 + rowbase + li) * 8];
}
__device__ inline s16x8 fldg(const ushort* w, int rowbase, int ks, int g, int li) {
    return *(const s16x8*)&w[(rowbase + li) * 64 + 32 * ks + 8 * g];
}

// LayerNorm, 512-thread version: 8 lanes per token, 8 channels each.
__device__ inline void ln_win512(const float* __restrict__ src,
                                 const float* __restrict__ lw, const float* __restrict__ lb,
                                 ushort* dsth, ushort* dstl, int wi, int wj, int tid)
{
    const int n = tid >> 3, p = tid & 7;
    const int gtok = (wi * 8 + (n >> 3)) * RES + wj * 8 + (n & 7);
    const float* rp = src + (size_t)gtok * DIMC + p * 8;
    float v[8];
    *(float4*)&v[0] = *(const float4*)&rp[0];
    *(float4*)&v[4] = *(const float4*)&rp[4];
    float s = 0.f, s2 = 0.f;
    #pragma unroll
    for (int j = 0; j < 8; ++j) { s += v[j]; s2 += v[j] * v[j]; }
    s  += __shfl_xor(s, 1);  s  += __shfl_xor(s, 2);  s  += __shfl_xor(s, 4);
    s2 += __shfl_xor(s2, 1); s2 += __shfl_xor(s2, 2); s2 += __shfl_xor(s2, 4);
    const float mean = s * 0.015625f;
    const float var  = s2 * 0.015625f - mean * mean;
    const float rs = rsqrtf(var + 1e-5f);
    float wv[8], bv[8];
    *(float4*)&wv[0] = *(const float4*)&lw[p*8+0];  *(float4*)&bv[0] = *(const float4*)&lb[p*8+0];
    *(float4*)&wv[4] = *(const float4*)&lw[p*8+4];  *(float4*)&bv[4] = *(const float4*)&lb[p*8+4];
    unsigned pkh[4], pkl[4];
    #pragma unroll
    for (int j = 0; j < 4; ++j) {
        float a = (v[2*j]   - mean) * rs * wv[2*j]   + bv[2*j];
        float b = (v[2*j+1] - mean) * rs * wv[2*j+1] + bv[2*j+1];
        bfu ha = f2bf(a), hb = f2bf(b);
        bfu la = f2bf(a - bf2f(ha)), lb2 = f2bf(b - bf2f(hb));
        pkh[j] = (unsigned)ha | ((unsigned)hb << 16);
        pkl[j] = (unsigned)la | ((unsigned)lb2 << 16);
    }
    *(int4*)&dsth[(p * 64 + n) * 8] = *(const int4*)&pkh[0];
    *(int4*)&dstl[(p * 64 + n) * 8] = *(const int4*)&pkl[0];
}

// LayerNorm (sequential tokens, 256-thread) -> hi/lo chunked (for k_fc1)
__device__ inline void ln_seq2(const float* __restrict__ src,
                               const float* __restrict__ lw, const float* __restrict__ lb,
                               ushort* dsth, ushort* dstl, int base, int tid)
{
    const int n = tid >> 2, p = tid & 3;
    const int gtok = base + n;
    const float* rp = src + (size_t)gtok * DIMC + p * 16;
    float v[16];
    *(float4*)&v[0]  = *(const float4*)&rp[0];
    *(float4*)&v[4]  = *(const float4*)&rp[4];
    *(float4*)&v[8]  = *(const float4*)&rp[8];
    *(float4*)&v[12] = *(const float4*)&rp[12];
    float s = 0.f, s2 = 0.f;
    #pragma unroll
    for (int j = 0; j < 16; ++j) { s += v[j]; s2 += v[j] * v[j]; }
    s  += __shfl_xor(s, 1);  s  += __shfl_xor(s, 2);
    s2 += __shfl_xor(s2, 1); s2 += __shfl_xor(s2, 2);
    const float mean = s * 0.015625f;
    const float var  = s2 * 0.015625f - mean * mean;
    const float rs = rsqrtf(var + 1e-5f);
    float wv[16], bv[16];
    *(float4*)&wv[0]  = *(const float4*)&lw[p*16+0];  *(float4*)&bv[0]  = *(const float4*)&lb[p*16+0];
    *(float4*)&wv[4]  = *(const float4*)&lw[p*16+4];  *(float4*)&bv[4]  = *(const float4*)&lb[p*16+4];
    *(float4*)&wv[8]  = *(const float4*)&lw[p*16+8];  *(float4*)&bv[8]  = *(const float4*)&lb[p*16+8];
    *(float4*)&wv[12] = *(const float4*)&lw[p*16+12]; *(float4*)&bv[12] = *(const float4*)&lb[p*16+12];
    unsigned pkh[8], pkl[8];
    #pragma unroll
    for (int j = 0; j < 8; ++j) {
        float a = (v[2*j]   - mean) * rs * wv[2*j]   + bv[2*j];
        float b = (v[2*j+1] - mean) * rs * wv[2*j+1] + bv[2*j+1];
        bfu ha = f2bf(a), hb = f2bf(b);
        bfu la = f2bf(a - bf2f(ha)), lb2 = f2bf(b - bf2f(hb));
        pkh[j] = (unsigned)ha | ((unsigned)hb << 16);
        pkl[j] = (unsigned)la | ((unsigned)lb2 << 16);
    }
    *(int4*)&dsth[((2*p)   * 64 + n) * 8] = *(const int4*)&pkh[0];
    *(int4*)&dsth[((2*p+1) * 64 + n) * 8] = *(const int4*)&pkh[4];
    *(int4*)&dstl[((2*p)   * 64 + n) * 8] = *(const int4*)&pkl[0];
    *(int4*)&dstl[((2*p+1) * 64 + n) * 8] = *(const int4*)&pkl[4];
}

// Split-precision transposed projection, HALF version: ct in {2cth, 2cth+1}.
__device__ inline void gemmT3h(const ushort* __restrict__ wTh, const ushort* __restrict__ wTl,
                               const ushort* xh, const ushort* xl,
                               const float* __restrict__ biasv,
                               ushort* dst, int w, int cth, int g, int li)
{
    const s16x8 ah0 = fldg(wTh, 16*w, 0, g, li);
    const s16x8 ah1 = fldg(wTh, 16*w, 1, g, li);
    const s16x8 al0 = fldg(wTl, 16*w, 0, g, li);
    const s16x8 al1 = fldg(wTl, 16*w, 1, g, li);
    const float4 bias = *(const float4*)&biasv[16*w + 4*g];
    #pragma unroll
    for (int c2 = 0; c2 < 2; ++c2) {
        const int ct = 2*cth + c2;
        const s16x8 bh0 = fldl(xh, 0, 16*ct, g, li);
        const s16x8 bh1 = fldl(xh, 4, 16*ct, g, li);
        const s16x8 bl0 = fldl(xl, 0, 16*ct, g, li);
        const s16x8 bl1 = fldl(xl, 4, 16*ct, g, li);
        f32x4 acc = {0.f, 0.f, 0.f, 0.f};
        acc = MFMA(al0, bh0, acc);
        acc = MFMA(al1, bh1, acc);
        acc = MFMA(ah0, bl0, acc);
        acc = MFMA(ah1, bl1, acc);
        acc = MFMA(ah0, bh0, acc);
        acc = MFMA(ah1, bh1, acc);
        *(ushort4*)&dst[((2*w + (g>>1)) * 64 + 16*ct + li) * 8 + (g&1)*4] =
            pack4(acc[0]+bias.x, acc[1]+bias.y, acc[2]+bias.z, acc[3]+bias.w);
    }
}

// HALF version, f32 store (stride 68): token = 16ct+li, channel = 16w+4g+r.
__device__ inline void gemmT3fh(const ushort* __restrict__ wTh, const ushort* __restrict__ wTl,
                                const ushort* xh, const ushort* xl,
                                const float* __restrict__ biasv,
                                float* dst, int w, int cth, int g, int li)
{
    const s16x8 ah0 = fldg(wTh, 16*w, 0, g, li);
    const s16x8 ah1 = fldg(wTh, 16*w, 1, g, li);
    const s16x8 al0 = fldg(wTl, 16*w, 0, g, li);
    const s16x8 al1 = fldg(wTl, 16*w, 1, g, li);
    const float4 bias = *(const float4*)&biasv[16*w + 4*g];
    #pragma unroll
    for (int c2 = 0; c2 < 2; ++c2) {
        const int ct = 2*cth + c2;
        const s16x8 bh0 = fldl(xh, 0, 16*ct, g, li);
        const s16x8 bh1 = fldl(xh, 4, 16*ct, g, li);
        const s16x8 bl0 = fldl(xl, 0, 16*ct, g, li);
        const s16x8 bl1 = fldl(xl, 4, 16*ct, g, li);
        f32x4 acc = {0.f, 0.f, 0.f, 0.f};
        acc = MFMA(al0, bh0, acc);
        acc = MFMA(al1, bh1, acc);
        acc = MFMA(ah0, bl0, acc);
        acc = MFMA(ah1, bl1, acc);
        acc = MFMA(ah0, bh0, acc);
        acc = MFMA(ah1, bh1, acc);
        float4 st = { acc[0]+bias.x, acc[1]+bias.y, acc[2]+bias.z, acc[3]+bias.w };
        *(float4*)&dst[(16*ct + li)*68 + 16*w + 4*g] = st;
    }
}

// Full version (256-thread kernels), bf16 chunked store.
__device__ inline void gemmT3(const ushort* __restrict__ wTh, const ushort* __restrict__ wTl,
                              const ushort* xh, const ushort* xl,
                              const float* __restrict__ biasv,
                              ushort* dst, int w, int g, int li)
{
    const s16x8 ah0 = fldg(wTh, 16*w, 0, g, li);
    const s16x8 ah1 = fldg(wTh, 16*w, 1, g, li);
    const s16x8 al0 = fldg(wTl, 16*w, 0, g, li);
    const s16x8 al1 = fldg(wTl, 16*w, 1, g, li);
    const float4 bias = *(const float4*)&biasv[16*w + 4*g];
    #pragma unroll
    for (int ct = 0; ct < 4; ++ct) {
        const s16x8 bh0 = fldl(xh, 0, 16*ct, g, li);
        const s16x8 bh1 = fldl(xh, 4, 16*ct, g, li);
        const s16x8 bl0 = fldl(xl, 0, 16*ct, g, li);
        const s16x8 bl1 = fldl(xl, 4, 16*ct, g, li);
        f32x4 acc = {0.f, 0.f, 0.f, 0.f};
        acc = MFMA(al0, bh0, acc);
        acc = MFMA(al1, bh1, acc);
        acc = MFMA(ah0, bl0, acc);
        acc = MFMA(ah1, bl1, acc);
        acc = MFMA(ah0, bh0, acc);
        acc = MFMA(ah1, bh1, acc);
        *(ushort4*)&dst[((2*w + (g>>1)) * 64 + 16*ct + li) * 8 + (g&1)*4] =
            pack4(acc[0]+bias.x, acc[1]+bias.y, acc[2]+bias.z, acc[3]+bias.w);
    }
}

// ---------------------------------------------------------------------------
// Prep: attn tables (12 matrices, bsc, bias2) + fc1/fc2 transposed hi/lo.
// ---------------------------------------------------------------------------
__global__ __launch_bounds__(256) void k_prep(
    const float* __restrict__ wqx, const float* __restrict__ wkvx,
    const float* __restrict__ wqf, const float* __restrict__ wkvf,
    const float* __restrict__ projw, const float* __restrict__ bqx,
    const float* __restrict__ bqf, const float* __restrict__ rpb,
    const float* __restrict__ fc1w, const float* __restrict__ fc2w,
    ushort* __restrict__ wb, float* __restrict__ bsc, float* __restrict__ bias2)
{
    const float scale = 0.17677669529663687f;  // 32^-0.5
    int t = blockIdx.x * 256 + threadIdx.x;
    if (t < 49152) {
        int m = t >> 12, idx = t & 4095;
        int c = idx >> 6, k = idx & 63;
        int mm = m % 6;
        float val;
        switch (mm) {
            case 0:  val = wqx [k*64  + c] * scale; break;
            case 1:  val = wkvx[k*128 + c];         break;
            case 2:  val = wkvx[k*128 + 64 + c];    break;
            case 3:  val = wqf [k*64  + c] * scale; break;
            case 4:  val = wkvf[k*128 + c];         break;
            default: val = projw[k*64 + c];         break;
        }
        bfu h = f2bf(val);
        wb[m*4096 + c*64 + k] = (m < 6) ? h : f2bf(val - bf2f(h));
    } else if (t < 65536) {            // fc1^T hi+lo: [256 out][64 k]
        int i = t - 49152;
        int c = i >> 6, k = i & 63;
        float val = fc1w[k*HIDC + c];
        bfu h = f2bf(val);
        wb[49152 + i] = h;
        wb[65536 + i] = f2bf(val - bf2f(h));
    } else if (t < 81920) {            // fc2^T hi+lo: [64 out][256 k]
        int i = t - 65536;
        int c = i >> 8, k = i & 255;
        float val = fc2w[k*DIMC + c];
        bfu h = f2bf(val);
        wb[81920 + i] = h;
        wb[98304 + i] = f2bf(val - bf2f(h));
    } else if (t < 82048) {
        int i = t - 81920;
        bsc[i] = (i < 64) ? bqx[i] * scale : bqf[i-64] * scale;
    } else if (t < 90240) {
        int i = t - 82048;
        int h = i >> 12, rest = i & 4095;
        int n = rest >> 6, m2 = rest & 63;
        int idx = ((n>>3) - (m2>>3) + 7) * 15 + ((n&7) - (m2&7) + 7);
        bias2[h*4096 + rest] = rpb[idx*2 + h];
    }
}

// ---------------------------------------------------------------------------
// Kernel A (R13, bit-proven): 512 threads / window.
// ---------------------------------------------------------------------------
__global__ __launch_bounds__(512, 4) void k_attn(
    const float* __restrict__ x, const float* __restrict__ f,
    const float* __restrict__ n1w, const float* __restrict__ n1b,
    const float* __restrict__ n1fw, const float* __restrict__ n1fb,
    const float* __restrict__ bkvx, const float* __restrict__ bkvf,
    const float* __restrict__ projw32, const float* __restrict__ projb,
    const ushort* __restrict__ wbufs, const float* __restrict__ bsc,
    const float* __restrict__ bias2,
    float* __restrict__ xmid)
{
    __shared__ __align__(16) unsigned char LDSRAW[75776];
    ushort* bufA   = (ushort*)(LDSRAW);
    ushort* bufAlo = (ushort*)(LDSRAW + 8192);
    ushort* bufQF  = (ushort*)(LDSRAW + 16384);
    ushort* bufKF  = (ushort*)(LDSRAW + 24576);
    ushort* bufQ   = (ushort*)(LDSRAW + 32768);
    float*  Kf32   = (float*)(LDSRAW + 40960);
    float*  Vf32   = (float*)(LDSRAW + 58368);
    float*  Pf     = (float*)(LDSRAW);            // [2][64][65]
    float*  Of     = (float*)(LDSRAW + 33280);    // [64][68]
    float*  Wlds   = (float*)(LDSRAW);            // [64][68] after Ph5

    const int tid = (int)threadIdx.x;
    const int wv = tid >> 6, lane = tid & 63, g = lane >> 4, li = lane & 15;
    const int wid = blockIdx.x, wi = wid >> 6, wj = wid & 63;
    const int w8 = wv & 3, cth = wv >> 2;         // gemm split

    const ushort* wqxTh  = wbufs;
    const ushort* wkxTh  = wbufs + 4096;
    const ushort* wvxTh  = wbufs + 8192;
    const ushort* wqfTh  = wbufs + 12288;
    const ushort* wkfTh  = wbufs + 16384;
    const ushort* wqxTl  = wbufs + 24576;
    const ushort* wkxTl  = wbufs + 28672;
    const ushort* wvxTl  = wbufs + 32768;
    const ushort* wqfTl  = wbufs + 36864;
    const ushort* wkfTl  = wbufs + 40960;
    const float* bqxs = bsc, * bqfs = bsc + 64;

    // Ph0: LN(f) -> A(hi), Alo(lo)
    ln_win512(f, n1fw, n1fb, bufA, bufAlo, wi, wj, tid);
    __syncthreads();

    // Ph1: qf -> QF, kf -> KF (each wave does half of each gemm)
    gemmT3h(wqfTh, wqfTl, bufA, bufAlo, bqfs, bufQF, w8, cth, g, li);
    gemmT3h(wkfTh, wkfTl, bufA, bufAlo, bkvf, bufKF, w8, cth, g, li);
    __syncthreads();

    // Ph2: LN(x) -> A/Alo (fn dead)
    ln_win512(x, n1w, n1b, bufA, bufAlo, wi, wj, tid);
    __syncthreads();

    // Ph3: q -> Q (bf16), k -> Kf32, v -> Vf32
    gemmT3h (wqxTh, wqxTl, bufA, bufAlo, bqxs,      bufQ, w8, cth, g, li);
    gemmT3fh(wkxTh, wkxTl, bufA, bufAlo, bkvx,      Kf32, w8, cth, g, li);
    gemmT3fh(wvxTh, wvxTl, bufA, bufAlo, bkvx + 64, Vf32, w8, cth, g, li);
    __syncthreads();

    // Ph4: fused S_f + S_x + joint logits + softmax, all in registers.
    const int h2 = tid >> 8, q2 = (tid >> 2) & 63, kh = tid & 3;
    float p[16];
    float den;
    {
        float qfreg[32], qreg[32];
        #pragma unroll
        for (int cc = 0; cc < 4; ++cc) {
            const s16x8 qfv = *(const s16x8*)&bufQF[((4*h2+cc)*64 + q2)*8];
            const s16x8 qv  = *(const s16x8*)&bufQ [((4*h2+cc)*64 + q2)*8];
            #pragma unroll
            for (int j = 0; j < 8; ++j) {
                qfreg[8*cc+j] = bf2f((bfu)(unsigned short)qfv[j]);
                qreg [8*cc+j] = bf2f((bfu)(unsigned short)qv[j]);
            }
        }
        const float* brow = &bias2[h2*4096 + q2*64];
        float mx = -1e30f;
        #pragma unroll
        for (int mi = 0; mi < 16; ++mi) {
            const int m = 4*mi + kh;
            float sf = 0.f, sx = 0.f;
            #pragma unroll
            for (int cc = 0; cc < 4; ++cc) {
                const s16x8 kfv = *(const s16x8*)&bufKF[((4*h2+cc)*64 + m)*8];
                #pragma unroll
                for (int j = 0; j < 8; ++j) sf += qfreg[8*cc+j] * bf2f((bfu)(unsigned short)kfv[j]);
            }
            #pragma unroll
            for (int c4 = 0; c4 < 8; ++c4) {
                const float4 kv = *(const float4*)&Kf32[m*68 + 32*h2 + 4*c4];
                sx += qreg[4*c4+0]*kv.x + qreg[4*c4+1]*kv.y
                    + qreg[4*c4+2]*kv.z + qreg[4*c4+3]*kv.w;
            }
            const float b = brow[m];
            const float lv = (sx + b) * (sf + b);
            p[mi] = lv;
            mx = fmaxf(mx, lv);
        }
        mx = fmaxf(mx, __shfl_xor(mx, 1));
        mx = fmaxf(mx, __shfl_xor(mx, 2));
        den = 0.f;
        #pragma unroll
        for (int mi = 0; mi < 16; ++mi) {
            const float e = __expf(p[mi] - mx);
            p[mi] = e;
            den += e;
        }
        den += __shfl_xor(den, 1);
        den += __shfl_xor(den, 2);
    }
    __syncthreads();   // q/qf/kf/K reads complete; P may overwrite

    // Ph4b: P (f32, stride 65) -> Pf; den -> row slot 64
    {
        float* srow = &Pf[h2*4160 + q2*65];
        #pragma unroll
        for (int mi = 0; mi < 16; ++mi) srow[4*mi + kh] = p[mi];
        if (kh == 0) srow[64] = den;
    }
    __syncthreads();

    // Ph5: PV (f32). wave -> (head, channel-octet); lane = query
    {
        const int comp = wv;
        const int head = comp >> 2, quarter = comp & 3;
        const int cbase = head*32 + quarter*8;
        const int n2 = lane;
        float acc[8];
        #pragma unroll
        for (int j = 0; j < 8; ++j) acc[j] = 0.f;
        const float* prow = &Pf[head*4160 + n2*65];
        for (int m = 0; m < 64; ++m) {
            const float pv = prow[m];
            #pragma unroll
            for (int c4 = 0; c4 < 2; ++c4) {
                const float4 vv = *(const float4*)&Vf32[m*68 + cbase + 4*c4];
                acc[4*c4+0] += pv * vv.x;
                acc[4*c4+1] += pv * vv.y;
                acc[4*c4+2] += pv * vv.z;
                acc[4*c4+3] += pv * vv.w;
            }
        }
        const float inv = 1.f / prow[64];
        #pragma unroll
        for (int j4 = 0; j4 < 2; ++j4) {
            float4 st = { acc[4*j4]*inv, acc[4*j4+1]*inv, acc[4*j4+2]*inv, acc[4*j4+3]*inv };
            *(float4*)&Of[n2*68 + cbase + 4*j4] = st;
        }
    }
    __syncthreads();   // P dead; W may overwrite

    // Ph5c: stage projw -> Wlds [64][68] (L2-hot 16KB, coalesced)
    {
        const int row = tid >> 3, c = (tid & 7) * 8;
        const float4 w0 = *(const float4*)&projw32[row*64 + c];
        const float4 w1 = *(const float4*)&projw32[row*64 + c + 4];
        *(float4*)&Wlds[row*68 + c]     = w0;
        *(float4*)&Wlds[row*68 + c + 4] = w1;
    }
    __syncthreads();

    // Ph6: proj from LDS + bias + residual -> xmid. thread = (token, 8-ch group)
    {
        const int n = tid >> 3, c0q = (tid & 7) * 8;
        float acc2[8];
        *(float4*)&acc2[0] = *(const float4*)&projb[c0q];
        *(float4*)&acc2[4] = *(const float4*)&projb[c0q + 4];
        for (int kk = 0; kk < 64; ++kk) {
            const float a = Of[n*68 + kk];
            const float* wr = Wlds + kk*68 + c0q;
            #pragma unroll
            for (int j = 0; j < 8; ++j) acc2[j] += a * wr[j];
        }
        const int gtok = (wi*8 + (n >> 3)) * RES + wj*8 + (n & 7);
        const float4 r0 = *(const float4*)&x[(size_t)gtok*DIMC + c0q];
        const float4 r1 = *(const float4*)&x[(size_t)gtok*DIMC + c0q + 4];
        float4 o0 = { acc2[0]+r0.x, acc2[1]+r0.y, acc2[2]+r0.z, acc2[3]+r0.w };
        float4 o1 = { acc2[4]+r1.x, acc2[5]+r1.y, acc2[6]+r1.z, acc2[7]+r1.w };
        *(float4*)&xmid[(size_t)gtok*DIMC + c0q]     = o0;
        *(float4*)&xmid[(size_t)gtok*DIMC + c0q + 4] = o1;
    }
}

// ---------------------------------------------------------------------------
// Kernel B (MFMA): LN(xmid) -> fc1 (split-precision) -> y1 (bf16).
// ---------------------------------------------------------------------------
__global__ __launch_bounds__(256) void k_fc1(
    const float* __restrict__ xm,
    const float* __restrict__ n2w, const float* __restrict__ n2b,
    const ushort* __restrict__ fc1h, const ushort* __restrict__ fc1l,
    const float* __restrict__ fc1b,
    bfu* __restrict__ y1)
{
    __shared__ __align__(16) ushort xh[4096], xl[4096];
    const int tid = (int)threadIdx.x, wv = tid >> 6, lane = tid & 63;
    const int g = lane >> 4, li = lane & 15;
    const int base = blockIdx.x * 64;

    ln_seq2(xm, n2w, n2b, xh, xl, base, tid);
    __syncthreads();

    #pragma unroll
    for (int ot = 0; ot < 4; ++ot) {
        const int chb = 64*wv + 16*ot;
        const s16x8 ah0 = fldg(fc1h, chb, 0, g, li);
        const s16x8 ah1 = fldg(fc1h, chb, 1, g, li);
        const s16x8 al0 = fldg(fc1l, chb, 0, g, li);
        const s16x8 al1 = fldg(fc1l, chb, 1, g, li);
        const float4 bb = *(const float4*)&fc1b[chb + 4*g];
        #pragma unroll
        for (int ct = 0; ct < 4; ++ct) {
            const s16x8 bh0 = fldl(xh, 0, 16*ct, g, li);
            const s16x8 bh1 = fldl(xh, 4, 16*ct, g, li);
            const s16x8 bl0 = fldl(xl, 0, 16*ct, g, li);
            const s16x8 bl1 = fldl(xl, 4, 16*ct, g, li);
            f32x4 acc = {0.f, 0.f, 0.f, 0.f};
            acc = MFMA(al0, bh0, acc);
            acc = MFMA(al1, bh1, acc);
            acc = MFMA(ah0, bl0, acc);
            acc = MFMA(ah1, bl1, acc);
            acc = MFMA(ah0, bh0, acc);
            acc = MFMA(ah1, bh1, acc);
            const int tok = base + 16*ct + li;
            *(ushort4*)&y1[(size_t)tok*HIDC + chb + 4*g] =
                pack4(acc[0]+bb.x, acc[1]+bb.y, acc[2]+bb.z, acc[3]+bb.w);
        }
    }
}

// ---------------------------------------------------------------------------
// Kernel C: depthwise 3x3 conv + relu (VALU, R13 bit-proven loop; conv
// weights read direct from global, no LDS staging) -> fc2 (split-MFMA)
// + bias + residual, in-place on d_out. Block = 32 tokens. 4 blocks/CU.
// ---------------------------------------------------------------------------
__global__ __launch_bounds__(256, 4) void k_conv_fc2(
    const bfu* __restrict__ y1,
    const float* __restrict__ cw, const float* __restrict__ cb,
    const ushort* __restrict__ fc2h, const ushort* __restrict__ fc2l,
    const float* __restrict__ fc2b,
    float* __restrict__ xout)
{
    __shared__ __align__(16) ushort chH[8192], chL[8192];  // [32 tok][256 ch] chunked
    const int tid = (int)threadIdx.x, wv = tid >> 6, lane = tid & 63;
    const int g = lane >> 4, li = lane & 15;

    const int base = blockIdx.x * 32;
    const int ch0 = lane * 4;

    // conv weights: direct global reads (9KB table, L1/L2-hot across blocks)
    float kw[4][9];
    #pragma unroll
    for (int j = 0; j < 4; ++j)
        #pragma unroll
        for (int kidx = 0; kidx < 9; ++kidx) kw[j][kidx] = cw[(ch0+j)*9 + kidx];
    const float cb0 = cb[ch0], cb1 = cb[ch0+1], cb2 = cb[ch0+2], cb3 = cb[ch0+3];

    for (int t = 0; t < 8; ++t) {
        const int tr = wv * 8 + t;
        const int tok = base + tr;
        const int hh = tok >> 9, ww = tok & 511;
        float a0 = cb0, a1 = cb1, a2 = cb2, a3 = cb3;
        #pragma unroll
        for (int dh = -1; dh <= 1; ++dh) {
            const int h2 = hh + dh;
            if (h2 < 0 || h2 >= RES) continue;
            #pragma unroll
            for (int dw = -1; dw <= 1; ++dw) {
                const int w2 = ww + dw;
                if (w2 < 0 || w2 >= RES) continue;
                const ushort4 u = *(const ushort4*)&y1[(size_t)(h2*RES + w2)*HIDC + ch0];
                const int kidx = (dh+1)*3 + (dw+1);
                a0 += bf2f(u.x) * kw[0][kidx];
                a1 += bf2f(u.y) * kw[1][kidx];
                a2 += bf2f(u.z) * kw[2][kidx];
                a3 += bf2f(u.w) * kw[3][kidx];
            }
        }
        a0 = fmaxf(a0, 0.f); a1 = fmaxf(a1, 0.f);
        a2 = fmaxf(a2, 0.f); a3 = fmaxf(a3, 0.f);
        ushort4 hi, lo;
        hi.x = f2bf(a0); lo.x = f2bf(a0 - bf2f(hi.x));
        hi.y = f2bf(a1); lo.y = f2bf(a1 - bf2f(hi.y));
        hi.z = f2bf(a2); lo.z = f2bf(a2 - bf2f(hi.z));
        hi.w = f2bf(a3); lo.w = f2bf(a3 - bf2f(hi.w));
        const int cidx = ((ch0 >> 3) * 32 + tr) * 8 + (ch0 & 7);
        *(ushort4*)&chH[cidx] = hi;
        *(ushort4*)&chL[cidx] = lo;
    }
    __syncthreads();

    // fc2: wave wv -> out-channel tile 16*wv; K=256 (8 k-steps x 3 split terms)
    {
        const int chb = 16 * wv;
        f32x4 accA = {0.f, 0.f, 0.f, 0.f};
        f32x4 accB = {0.f, 0.f, 0.f, 0.f};
        #pragma unroll
        for (int ks = 0; ks < 8; ++ks) {
            const s16x8 ah = *(const s16x8*)&fc2h[(chb + li)*256 + 32*ks + 8*g];
            const s16x8 al = *(const s16x8*)&fc2l[(chb + li)*256 + 32*ks + 8*g];
            const s16x8 bh0 = *(const s16x8*)&chH[((4*ks + g)*32 + li) * 8];
            const s16x8 bl0 = *(const s16x8*)&chL[((4*ks + g)*32 + li) * 8];
            const s16x8 bh1 = *(const s16x8*)&chH[((4*ks + g)*32 + 16 + li) * 8];
            const s16x8 bl1 = *(const s16x8*)&chL[((4*ks + g)*32 + 16 + li) * 8];
            accA = MFMA(al, bh0, accA);
            accA = MFMA(ah, bl0, accA);
            accA = MFMA(ah, bh0, accA);
            accB = MFMA(al, bh1, accB);
            accB = MFMA(ah, bl1, accB);
            accB = MFMA(ah, bh1, accB);
        }
        const float4 bb = *(const float4*)&fc2b[chb + 4*g];
        {
            const int tok = base + li;
            float4 res = *(const float4*)&xout[(size_t)tok*DIMC + chb + 4*g];
            float4 o;
            o.x = res.x + accA[0] + bb.x;
            o.y = res.y + accA[1] + bb.y;
            o.z = res.z + accA[2] + bb.z;
            o.w = res.w + accA[3] + bb.w;
            *(float4*)&xout[(size_t)tok*DIMC + chb + 4*g] = o;
        }
        {
            const int tok = base + 16 + li;
            float4 res = *(const float4*)&xout[(size_t)tok*DIMC + chb + 4*g];
            float4 o;
            o.x = res.x + accB[0] + bb.x;
            o.y = res.y + accB[1] + bb.y;
            o.z = res.z + accB[2] + bb.z;
            o.w = res.w + accB[3] + bb.w;
            *(float4*)&xout[(size_t)tok*DIMC + chb + 4*g] = o;
        }
    }
}

// ---------------------------------------------------------------------------
extern "C" void kernel_launch(void* const* d_in, const int* in_sizes, int n_in,
                              void* d_out, int out_size, void* d_ws, size_t ws_size,
                              hipStream_t stream)
{
    const float* x    = (const float*)d_in[0];
    const float* f    = (const float*)d_in[1];
    const float* n1w  = (const float*)d_in[2];
    const float* n1b  = (const float*)d_in[3];
    const float* n1fw = (const float*)d_in[4];
    const float* n1fb = (const float*)d_in[5];
    const float* wqx  = (const float*)d_in[6];
    const float* bqx  = (const float*)d_in[7];
    const float* wkvx = (const float*)d_in[8];
    const float* bkvx = (const float*)d_in[9];
    const float* wqf  = (const float*)d_in[10];
    const float* bqf  = (const float*)d_in[11];
    const float* wkvf = (const float*)d_in[12];
    const float* bkvf = (const float*)d_in[13];
    const float* rpb  = (const float*)d_in[14];
    const float* projw= (const float*)d_in[15];
    const float* projb= (const float*)d_in[16];
    const float* n2w  = (const float*)d_in[17];
    const float* n2b  = (const float*)d_in[18];
    const float* fc1w = (const float*)d_in[19];
    const float* fc1b = (const float*)d_in[20];
    const float* cw   = (const float*)d_in[21];
    const float* cb   = (const float*)d_in[22];
    const float* fc2w = (const float*)d_in[23];
    const float* fc2b = (const float*)d_in[24];
    float* out = (float*)d_out;

    // Layout: y1 in ws (128 MiB); tables after it; xmid lives in d_out.
    bfu* y1 = (bfu*)d_ws;
    char* tb = (char*)d_ws + (size_t)LTOK * HIDC * 2;
    ushort* wb   = (ushort*)tb;                 // 114688 ushorts = 224 KiB
    float* bsc   = (float*)(tb + 229376);       // 128 f32
    float* bias2 = (float*)(tb + 229888);       // 8192 f32
    float* xmid  = out;                         // d_out doubles as xmid scratch

    hipLaunchKernelGGL(k_prep, dim3(353), dim3(256), 0, stream,
                       wqx, wkvx, wqf, wkvf, projw, bqx, bqf, rpb, fc1w, fc2w,
                       wb, bsc, bias2);
    hipLaunchKernelGGL(k_attn, dim3(NWIN), dim3(512), 0, stream,
                       x, f, n1w, n1b, n1fw, n1fb, bkvx, bkvf, projw, projb,
                       wb, bsc, bias2, xmid);
    hipLaunchKernelGGL(k_fc1, dim3(LTOK/64), dim3(256), 0, stream,
                       xmid, n2w, n2b, wb + 49152, wb + 65536, fc1b, y1);
    hipLaunchKernelGGL(k_conv_fc2, dim3(LTOK/32), dim3(256), 0, stream,
                       y1, cw, cb, wb + 81920, wb + 98304, fc2b, xmid);
}